// Round 1
// baseline (150.723 us; speedup 1.0000x reference)
//
#include <hip/hip_runtime.h>
#include <math.h>

#define T_TOK 8192
#define C_DIM 768
#define H_DIM 64
// reference MULTIPLIES by c**0.5; we work in exp2 domain: scale * log2(e)
#define SCALE_LOG2E (27.712812921102035f * 1.4426950408889634f)
#define NSPLIT 4

typedef _Float16 half8 __attribute__((ext_vector_type(8)));
typedef float floatx4 __attribute__((ext_vector_type(4)));

#define MFMA16(a, b, c) __builtin_amdgcn_mfma_f32_16x16x32_f16(a, b, c, 0, 0, 0)
// wait lgkmcnt(0) only: vmcnt=0x3F, expcnt=7, lgkm=0
#define WAIT_LGKM0() __builtin_amdgcn_s_waitcnt(0xC07F)
#define EXP2F(x) __builtin_amdgcn_exp2f(x)

// Fragment layouts in workspace (all 1KB frags, perfectly coalesced b128/lane):
//   WF[mat][kt(24)][nb(4)][hl(2)][512 f16]   = W[kt*32+quad*8+j][nb*16+l15]
//   KF[t(128)][nb(4)][ks(2)][hl(2)][512 f16] = K[t*64+nb*16+l15][ks*32+quad*8+j]
//   QF[rb(512)][ks(2)][hl(2)][512 f16]       = Q[rb*16+l15][ks*32+quad*8+j]
//   VF[t(128)][nb(4)][ks(2)][512 f16]        = V[t*64+ks*32+quad*8+j][nb*16+l15]

// ---------------------------------------------------------------------------
// Kernel 0: W fp32 -> hi/lo f16 B-frags.  288 blocks x 64 threads.
// (byte-identical to the round-10 passing version)
// ---------------------------------------------------------------------------
__global__ __launch_bounds__(64) void wconvert_kernel(
    const float* __restrict__ Wk, const float* __restrict__ Wq,
    const float* __restrict__ Wv, _Float16* __restrict__ WF)
{
    const int b = blockIdx.x;                  // 3*24*4
    const int mat = b / 96, rem = b % 96, kt = rem >> 2, nb = rem & 3;
    const int lane = threadIdx.x & 63, l15 = lane & 15, quad = lane >> 4;
    const float* __restrict__ W = (mat == 0) ? Wk : (mat == 1) ? Wq : Wv;

    half8 h, l;
#pragma unroll
    for (int j = 0; j < 8; ++j) {
        const float v = W[(kt * 32 + quad * 8 + j) * H_DIM + nb * 16 + l15];
        const _Float16 hv = (_Float16)v;
        h[j] = hv;
        l[j] = (_Float16)(v - (float)hv);
    }
    _Float16* dst = WF + ((((size_t)mat * 24 + kt) * 4 + nb) * 2) * 512 + lane * 8;
    *(half8*)dst = h;
    *(half8*)(dst + 512) = l;
}

// ---------------------------------------------------------------------------
// Kernel 1: FUSED MFMA projection — one block computes K, Q AND V for its 32
// token rows, reading tokens ONCE (was 3x: 75.5 -> 25.2 MB HBM).  The MFMA
// work per token load triples (56 MFMA/iter ~ 272cy), so the 4-deep token
// FIFO (refill interval ~225cy at 900cy HBM latency) now fully covers the
// load latency that previously dominated this kernel.  256 blocks x 1 wave;
// ~360 VGPR is fine for a single-wave block (launch_bounds(64,1)).
// W frags stay 2-stage prefetched (L2-resident, ~200cy).  All loops fully
// unrolled so FIFO slots / stages / guards are compile-time (round-11
// lesson: runtime-indexed local arrays go to scratch).
// Per-mat MFMA sequence and epilogue math are bit-identical to the previous
// version (same hh/hl/lh order into the same accumulator).
// ---------------------------------------------------------------------------
__global__ __launch_bounds__(64, 1) void proj_kernel(
    const float* __restrict__ tokens, const _Float16* __restrict__ WF,
    _Float16* __restrict__ KF, _Float16* __restrict__ QF,
    _Float16* __restrict__ VF)
{
    __shared__ float Cb[3 * 32 * 68];          // 26.1 KB
    const int b = blockIdx.x;                  // 256 blocks, 32 rows each
    const int lane = threadIdx.x & 63, l15 = lane & 15, quad = lane >> 4;
    const int row0 = b * 32;

    floatx4 acc[3][2][4];
#pragma unroll
    for (int mat = 0; mat < 3; ++mat)
#pragma unroll
        for (int mb = 0; mb < 2; ++mb)
#pragma unroll
            for (int nb = 0; nb < 4; ++nb) acc[mat][mb][nb] = 0;

    const _Float16* __restrict__ wK = WF + lane * 8;           // mat 0 base
    const _Float16* __restrict__ wQ = wK + 24 * 4 * 2 * 512;   // mat 1 base
    const _Float16* __restrict__ wV = wQ + 24 * 4 * 2 * 512;   // mat 2 base
    const float* __restrict__ xb0 = tokens + (size_t)(row0 + l15) * C_DIM + quad * 8;
    const float* __restrict__ xb1 = tokens + (size_t)(row0 + 16 + l15) * C_DIM + quad * 8;

    // token FIFO: 4 iterations deep (kt = 0..3)
    float4 tf[4][4];
#pragma unroll
    for (int d = 0; d < 4; ++d) {
        tf[d][0] = *(const float4*)(xb0 + d * 32);
        tf[d][1] = *(const float4*)(xb0 + d * 32 + 4);
        tf[d][2] = *(const float4*)(xb1 + d * 32);
        tf[d][3] = *(const float4*)(xb1 + d * 32 + 4);
    }
    // W 2-stage prefetch: K hi/lo, Q hi/lo, V hi (V needs no lo term)
    half8 wkh[2][4], wkl[2][4], wqh[2][4], wql[2][4], wvh[2][4];
#pragma unroll
    for (int nb = 0; nb < 4; ++nb) {
        wkh[0][nb] = *(const half8*)(wK + (size_t)(nb * 2) * 512);
        wkl[0][nb] = *(const half8*)(wK + (size_t)(nb * 2 + 1) * 512);
        wqh[0][nb] = *(const half8*)(wQ + (size_t)(nb * 2) * 512);
        wql[0][nb] = *(const half8*)(wQ + (size_t)(nb * 2 + 1) * 512);
        wvh[0][nb] = *(const half8*)(wV + (size_t)(nb * 2) * 512);
    }

#pragma unroll
    for (int kt = 0; kt < 24; ++kt) {
        const int slot = kt & 3;               // compile-time (full unroll)
        const int cur = kt & 1, nxt = cur ^ 1;
        const float4 x0 = tf[slot][0], x1 = tf[slot][1];
        const float4 x2 = tf[slot][2], x3 = tf[slot][3];

        // issue next W frags (1 iteration ahead; L2-resident ~200cy)
        if (kt < 23) {
            const int ktn = kt + 1;
#pragma unroll
            for (int nb = 0; nb < 4; ++nb) {
                wkh[nxt][nb] = *(const half8*)(wK + (size_t)((ktn * 4 + nb) * 2) * 512);
                wkl[nxt][nb] = *(const half8*)(wK + (size_t)((ktn * 4 + nb) * 2 + 1) * 512);
                wqh[nxt][nb] = *(const half8*)(wQ + (size_t)((ktn * 4 + nb) * 2) * 512);
                wql[nxt][nb] = *(const half8*)(wQ + (size_t)((ktn * 4 + nb) * 2 + 1) * 512);
                wvh[nxt][nb] = *(const half8*)(wV + (size_t)((ktn * 4 + nb) * 2) * 512);
            }
        }
        // refill token FIFO slot with kt+4 (guard is compile-time)
        if (kt + 4 < 24) {
            const int ktf = kt + 4;
            tf[slot][0] = *(const float4*)(xb0 + ktf * 32);
            tf[slot][1] = *(const float4*)(xb0 + ktf * 32 + 4);
            tf[slot][2] = *(const float4*)(xb1 + ktf * 32);
            tf[slot][3] = *(const float4*)(xb1 + ktf * 32 + 4);
        }

        // convert current A-tiles to hi/lo f16 (identical math to previous)
        half8 ah[2], al[2];
        {
            const float xs0[8] = {x0.x, x0.y, x0.z, x0.w, x1.x, x1.y, x1.z, x1.w};
            const float xs1[8] = {x2.x, x2.y, x2.z, x2.w, x3.x, x3.y, x3.z, x3.w};
#pragma unroll
            for (int e = 0; e < 8; ++e) {
                _Float16 hv = (_Float16)xs0[e];
                ah[0][e] = hv;
                al[0][e] = (_Float16)(xs0[e] - (float)hv);
                hv = (_Float16)xs1[e];
                ah[1][e] = hv;
                al[1][e] = (_Float16)(xs1[e] - (float)hv);
            }
        }

        // 56 MFMA: K,Q get hh+hl+lh (fp32 emulation), V gets hh only.
        // 24 independent accumulator chains -> plenty of MFMA-pipe ILP.
#pragma unroll
        for (int nb = 0; nb < 4; ++nb) {
#pragma unroll
            for (int mb = 0; mb < 2; ++mb) {
                acc[0][mb][nb] = MFMA16(ah[mb], wkh[cur][nb], acc[0][mb][nb]);
                acc[0][mb][nb] = MFMA16(ah[mb], wkl[cur][nb], acc[0][mb][nb]);
                acc[0][mb][nb] = MFMA16(al[mb], wkh[cur][nb], acc[0][mb][nb]);
                acc[1][mb][nb] = MFMA16(ah[mb], wqh[cur][nb], acc[1][mb][nb]);
                acc[1][mb][nb] = MFMA16(ah[mb], wql[cur][nb], acc[1][mb][nb]);
                acc[1][mb][nb] = MFMA16(al[mb], wqh[cur][nb], acc[1][mb][nb]);
                acc[2][mb][nb] = MFMA16(ah[mb], wvh[cur][nb], acc[2][mb][nb]);
            }
        }
    }

    // C-layout -> LDS (stride 68), all three mats, one wait
#pragma unroll
    for (int mat = 0; mat < 3; ++mat)
#pragma unroll
        for (int mb = 0; mb < 2; ++mb)
#pragma unroll
            for (int nb = 0; nb < 4; ++nb)
#pragma unroll
                for (int r = 0; r < 4; ++r)
                    Cb[mat * 2176 + (mb * 16 + quad * 4 + r) * 68 + nb * 16 + l15] =
                        acc[mat][mb][nb][r];
    __builtin_amdgcn_wave_barrier();
    WAIT_LGKM0();
    __builtin_amdgcn_wave_barrier();

    // K (mat 0) and Q (mat 1) epilogues: hi/lo frag writes (same as before,
    // with the old per-mat block index mi replaced by b)
#pragma unroll
    for (int nbL = 0; nbL < 2; ++nbL) {
#pragma unroll
        for (int ks = 0; ks < 2; ++ks) {
            // ---- K ----
            {
                const float* cp = Cb + (nbL * 16 + l15) * 68 + ks * 32 + quad * 8;
                const float4 c0 = *(const float4*)cp;
                const float4 c1 = *(const float4*)(cp + 4);
                const float cs[8] = {c0.x, c0.y, c0.z, c0.w, c1.x, c1.y, c1.z, c1.w};
                half8 h, l;
#pragma unroll
                for (int e = 0; e < 8; ++e) {
                    const _Float16 hv = (_Float16)cs[e];
                    h[e] = hv;
                    l[e] = (_Float16)(cs[e] - (float)hv);
                }
                const int t = b >> 1, nb = (b & 1) * 2 + nbL;
                _Float16* dst =
                    KF + (((size_t)(t * 4 + nb) * 2 + ks) * 2) * 512 + lane * 8;
                *(half8*)dst = h;
                *(half8*)(dst + 512) = l;
            }
            // ---- Q ----
            {
                const float* cp =
                    Cb + 2176 + (nbL * 16 + l15) * 68 + ks * 32 + quad * 8;
                const float4 c0 = *(const float4*)cp;
                const float4 c1 = *(const float4*)(cp + 4);
                const float cs[8] = {c0.x, c0.y, c0.z, c0.w, c1.x, c1.y, c1.z, c1.w};
                half8 h, l;
#pragma unroll
                for (int e = 0; e < 8; ++e) {
                    const _Float16 hv = (_Float16)cs[e];
                    h[e] = hv;
                    l[e] = (_Float16)(cs[e] - (float)hv);
                }
                const int rb = b * 2 + nbL;
                _Float16* dst = QF + (((size_t)rb * 2 + ks) * 2) * 512 + lane * 8;
                *(half8*)dst = h;
                *(half8*)(dst + 512) = l;
            }
        }
    }

    // V (mat 2) epilogue: our 32 rows are exactly one ks-half of token tile
    // t = b>>1  (rows b*32..b*32+31  ==  t*64 + (b&1)*32 + [0,32))
    {
        const int t = b >> 1, ks = b & 1;
#pragma unroll
        for (int nb = 0; nb < 4; ++nb) {
            half8 h;
#pragma unroll
            for (int j = 0; j < 8; ++j)
                h[j] = (_Float16)Cb[2 * 2176 + (quad * 8 + j) * 68 + nb * 16 + l15];
            *(half8*)(VF + ((size_t)(t * 4 + nb) * 2 + ks) * 512 + lane * 8) = h;
        }
    }
}

// ---------------------------------------------------------------------------
// Kernel 2: causal flash attention.
// (byte-identical to the round-10 passing version)
// ---------------------------------------------------------------------------
__global__ __launch_bounds__(512, 2) void attn_mfma_kernel(
    const _Float16* __restrict__ QF, const _Float16* __restrict__ KF,
    const _Float16* __restrict__ VF,
    float* __restrict__ pm, float* __restrict__ pl, float* __restrict__ po)
{
    // Ps: [w(8)][mb(2)][16 rows][stride 72 f16] = 36864 B (9216 floats).
    // Merge phase reuses the same region:
    //   mO: [slot(2)][mhalf(2)][32][64] floats  @ 0     (8192 floats)
    //   mM: [slot(2)][mhalf(2)][32]             @ 8192  (128 floats)
    //   mL: [slot(2)][mhalf(2)][32]             @ 8320  (128 floats)
    __shared__ __align__(16) float smemf[9216];
    _Float16* Ps = (_Float16*)smemf;

    const int w = threadIdx.x >> 6, lane = threadIdx.x & 63;
    const int l15 = lane & 15, quad = lane >> 4;
    const int mhalf = w & 1, ss = w >> 1;

    const int b = blockIdx.x;
    const int j = b & 255, hb = b >> 8;
    const int qt = (hb == 0) ? (j >> 1) : (127 - (j >> 1));
    const int sp = (hb << 1) | (j & 1);

    const int qbase = qt * 64;
    const int wrow0 = qbase + mhalf * 32;

    // Q A-frags (hi/lo), loaded once
    half8 qh[2][2], ql[2][2];
#pragma unroll
    for (int mb = 0; mb < 2; ++mb)
#pragma unroll
        for (int ks = 0; ks < 2; ++ks) {
            const int rb = qt * 4 + mhalf * 2 + mb;
            const _Float16* qp = QF + (((size_t)rb * 2 + ks) * 2) * 512 + lane * 8;
            qh[mb][ks] = *(const half8*)qp;
            ql[mb][ks] = *(const half8*)(qp + 512);
        }

    floatx4 O[2][4];
#pragma unroll
    for (int mb = 0; mb < 2; ++mb)
#pragma unroll
        for (int nb = 0; nb < 4; ++nb) O[mb][nb] = 0;
    float mreg[2][4], lreg[2][4];
#pragma unroll
    for (int mb = 0; mb < 2; ++mb)
#pragma unroll
        for (int r = 0; r < 4; ++r) { mreg[mb][r] = -INFINITY; lreg[mb][r] = 0.f; }

    const int t0 = sp + 4 * ss;
    half8 bh[4][2], bl[4][2];
    if (t0 <= qt) {                            // preload first tile's K frags
#pragma unroll
        for (int nb = 0; nb < 4; ++nb)
#pragma unroll
            for (int ks = 0; ks < 2; ++ks) {
                const _Float16* kp =
                    KF + (((size_t)(t0 * 4 + nb) * 2 + ks) * 2) * 512 + lane * 8;
                bh[nb][ks] = *(const half8*)kp;
                bl[nb][ks] = *(const half8*)(kp + 512);
            }
    }

    for (int t = t0; t <= qt; t += 16) {
        const int kb = t * 64;

        // V frags of THIS tile: issued ~600cy before their PV use
        half8 v0r[4], v1r[4];
#pragma unroll
        for (int nb = 0; nb < 4; ++nb) {
            const _Float16* vp = VF + ((size_t)(t * 4 + nb) * 2) * 512 + lane * 8;
            v0r[nb] = *(const half8*)vp;
            v1r[nb] = *(const half8*)(vp + 512);
        }

        // S = Q K^T (hi*hi + hi*lo + lo*hi), scaled into exp2 domain
        float sv[2][4][4];
#pragma unroll
        for (int mb = 0; mb < 2; ++mb)
#pragma unroll
            for (int nb = 0; nb < 4; ++nb) {
                floatx4 s = 0;
#pragma unroll
                for (int ks = 0; ks < 2; ++ks) {
                    s = MFMA16(qh[mb][ks], bh[nb][ks], s);
                    s = MFMA16(qh[mb][ks], bl[nb][ks], s);
                    s = MFMA16(ql[mb][ks], bh[nb][ks], s);
                }
#pragma unroll
                for (int r = 0; r < 4; ++r) sv[mb][nb][r] = s[r] * SCALE_LOG2E;
            }

        // prefetch NEXT tile's K frags (current ones are dead after S)
        if (t + 16 <= qt) {
            const int tn = t + 16;
#pragma unroll
            for (int nb = 0; nb < 4; ++nb)
#pragma unroll
                for (int ks = 0; ks < 2; ++ks) {
                    const _Float16* kp =
                        KF + (((size_t)(tn * 4 + nb) * 2 + ks) * 2) * 512 + lane * 8;
                    bh[nb][ks] = *(const half8*)kp;
                    bl[nb][ks] = *(const half8*)(kp + 512);
                }
        }

        if (kb + 63 > wrow0) {                 // diagonal tile: causal mask
#pragma unroll
            for (int mb = 0; mb < 2; ++mb) {
                const int rowbase = wrow0 + mb * 16 + quad * 4;
#pragma unroll
                for (int nb = 0; nb < 4; ++nb) {
                    const int col = kb + nb * 16 + l15;
#pragma unroll
                    for (int r = 0; r < 4; ++r)
                        if (col > rowbase + r) sv[mb][nb][r] = -INFINITY;
                }
            }
        }

        // online softmax (exp2 domain)
#pragma unroll
        for (int mb = 0; mb < 2; ++mb) {
#pragma unroll
            for (int r = 0; r < 4; ++r) {
                float rm = fmaxf(fmaxf(sv[mb][0][r], sv[mb][1][r]),
                                 fmaxf(sv[mb][2][r], sv[mb][3][r]));
                rm = fmaxf(rm, __shfl_xor(rm, 1));
                rm = fmaxf(rm, __shfl_xor(rm, 2));
                rm = fmaxf(rm, __shfl_xor(rm, 4));
                rm = fmaxf(rm, __shfl_xor(rm, 8));
                const float mnew = fmaxf(mreg[mb][r], rm);
                const float alpha = EXP2F(mreg[mb][r] - mnew);   // -inf -> 0
                float psum = 0.f;
#pragma unroll
                for (int nb = 0; nb < 4; ++nb) {
                    const float p = EXP2F(sv[mb][nb][r] - mnew);  // -inf -> 0
                    psum += p;
                    Ps[(w * 2 + mb) * 1152 + (quad * 4 + r) * 72 + nb * 16 + l15] =
                        (_Float16)p;
                }
                lreg[mb][r] = lreg[mb][r] * alpha + psum;
                mreg[mb][r] = mnew;
#pragma unroll
                for (int nb = 0; nb < 4; ++nb) O[mb][nb][r] *= alpha;
            }
        }

        // P: C-layout -> A-layout via wave-private LDS
        __builtin_amdgcn_wave_barrier();
        WAIT_LGKM0();
        __builtin_amdgcn_wave_barrier();
        half8 pa0[2], pa1[2];
#pragma unroll
        for (int mb = 0; mb < 2; ++mb) {
            const _Float16* pp = Ps + (w * 2 + mb) * 1152 + l15 * 72 + quad * 8;
            pa0[mb] = *(const half8*)pp;
            pa1[mb] = *(const half8*)(pp + 32);
        }

        // PV with the V frags loaded at tile top
#pragma unroll
        for (int nb = 0; nb < 4; ++nb) {
#pragma unroll
            for (int mb = 0; mb < 2; ++mb) {
                O[mb][nb] = MFMA16(pa0[mb], v0r[nb], O[mb][nb]);
                O[mb][nb] = MFMA16(pa1[mb], v1r[nb], O[mb][nb]);
            }
        }
        __builtin_amdgcn_wave_barrier();
    }

    // row-sum l across the 16-lane group (lane-local partials are exact
    // because alpha factors are row-uniform)
#pragma unroll
    for (int mb = 0; mb < 2; ++mb)
#pragma unroll
        for (int r = 0; r < 4; ++r) {
            float s = lreg[mb][r];
            s += __shfl_xor(s, 1);
            s += __shfl_xor(s, 2);
            s += __shfl_xor(s, 4);
            s += __shfl_xor(s, 8);
            lreg[mb][r] = s;
        }

    // ---- 2-round subsplit merge (proven pattern applied twice) ----
    __syncthreads();                           // Ps now dead; reuse as buffers
    // Round A: ss in {2,3} publish to slot ss-2
    if (ss >= 2) {
        const int slot = ss - 2;
#pragma unroll
        for (int mb = 0; mb < 2; ++mb)
#pragma unroll
            for (int r = 0; r < 4; ++r) {
                const int row32 = mb * 16 + quad * 4 + r;
                const int sidx = (slot * 2 + mhalf) * 32 + row32;
#pragma unroll
                for (int nb = 0; nb < 4; ++nb)
                    smemf[sidx * 64 + nb * 16 + l15] = O[mb][nb][r];
                if (l15 == 0) {
                    smemf[8192 + sidx] = mreg[mb][r];
                    smemf[8320 + sidx] = lreg[mb][r];
                }
            }
    }
    __syncthreads();
    if (ss < 2) {                              // ss0 <- slot0(ss2), ss1 <- slot1(ss3)
        const int slot = ss;
#pragma unroll
        for (int mb = 0; mb < 2; ++mb)
#pragma unroll
            for (int r = 0; r < 4; ++r) {
                const int row32 = mb * 16 + quad * 4 + r;
                const int sidx = (slot * 2 + mhalf) * 32 + row32;
                const float m1 = mreg[mb][r], l1 = lreg[mb][r];
                const float m2 = smemf[8192 + sidx];
                const float l2 = smemf[8320 + sidx];
                const float mm = fmaxf(m1, m2);
                const float a1 = (m1 == -INFINITY) ? 0.f : EXP2F(m1 - mm);
                const float a2 = (m2 == -INFINITY) ? 0.f : EXP2F(m2 - mm);
#pragma unroll
                for (int nb = 0; nb < 4; ++nb)
                    O[mb][nb][r] = O[mb][nb][r] * a1 +
                                   smemf[sidx * 64 + nb * 16 + l15] * a2;
                mreg[mb][r] = mm;
                lreg[mb][r] = l1 * a1 + l2 * a2;
            }
    }
    __syncthreads();
    // Round B: ss==1 publish merged state to slot 0
    if (ss == 1) {
#pragma unroll
        for (int mb = 0; mb < 2; ++mb)
#pragma unroll
            for (int r = 0; r < 4; ++r) {
                const int row32 = mb * 16 + quad * 4 + r;
                const int sidx = mhalf * 32 + row32;   // slot 0
#pragma unroll
                for (int nb = 0; nb < 4; ++nb)
                    smemf[sidx * 64 + nb * 16 + l15] = O[mb][nb][r];
                if (l15 == 0) {
                    smemf[8192 + sidx] = mreg[mb][r];
                    smemf[8320 + sidx] = lreg[mb][r];
                }
            }
    }
    __syncthreads();
    if (ss == 0) {                             // final merge + write partials
        const int pidx = qt * NSPLIT + sp;
#pragma unroll
        for (int mb = 0; mb < 2; ++mb)
#pragma unroll
            for (int r = 0; r < 4; ++r) {
                const int row32 = mb * 16 + quad * 4 + r;
                const int sidx = mhalf * 32 + row32;   // slot 0
                const float m1 = mreg[mb][r], l1 = lreg[mb][r];
                const float m2 = smemf[8192 + sidx];
                const float l2 = smemf[8320 + sidx];
                const float mm = fmaxf(m1, m2);
                const float a1 = (m1 == -INFINITY) ? 0.f : EXP2F(m1 - mm);
                const float a2 = (m2 == -INFINITY) ? 0.f : EXP2F(m2 - mm);
                const int row = mhalf * 32 + row32;
                float* dst = po + ((size_t)pidx * 64 + row) * 64;
#pragma unroll
                for (int nb = 0; nb < 4; ++nb)
                    dst[nb * 16 + l15] =
                        O[mb][nb][r] * a1 + smemf[sidx * 64 + nb * 16 + l15] * a2;
                if (l15 == 0) {
                    pm[pidx * 64 + row] = mm;
                    pl[pidx * 64 + row] = l1 * a1 + l2 * a2;
                }
            }
    }
}

// ---------------------------------------------------------------------------
// Kernel 3: merge the NSPLIT split-partials per row (exp2 domain).
// (byte-identical to the round-11 passing float4 version)
// ---------------------------------------------------------------------------
__global__ __launch_bounds__(256) void combine_kernel(
    const float* __restrict__ pm, const float* __restrict__ pl,
    const float* __restrict__ po, float* __restrict__ out)
{
    const int vid = blockIdx.x * 256 + threadIdx.x;    // over T*H/4
    const int row = vid >> 4;                          // 16 float4 per row
    const int d4  = vid & 15;
    const int qt  = row >> 6;
    const int r   = row & 63;

    float mm = -INFINITY;
#pragma unroll
    for (int s = 0; s < NSPLIT; ++s)
        mm = fmaxf(mm, pm[(qt * NSPLIT + s) * 64 + r]);
    float L = 0.f;
    float4 val = make_float4(0.f, 0.f, 0.f, 0.f);
#pragma unroll
    for (int s = 0; s < NSPLIT; ++s) {
        const int p = (qt * NSPLIT + s) * 64 + r;
        const float mp = pm[p];
        const float sc = (mp > -INFINITY) ? EXP2F(mp - mm) : 0.f;
        L += pl[p] * sc;
        const float4 v = *(const float4*)(po + (size_t)p * H_DIM + d4 * 4);
        val.x += v.x * sc; val.y += v.y * sc;
        val.z += v.z * sc; val.w += v.w * sc;
    }
    const float inv = 1.0f / L;
    float4 o; o.x = val.x * inv; o.y = val.y * inv;
    o.z = val.z * inv; o.w = val.w * inv;
    *(float4*)(out + (size_t)row * H_DIM + d4 * 4) = o;
}

// ---------------------------------------------------------------------------
extern "C" void kernel_launch(void* const* d_in, const int* in_sizes, int n_in,
                              void* d_out, int out_size, void* d_ws, size_t ws_size,
                              hipStream_t stream)
{
    const float* tokens = (const float*)d_in[0];
    const float* Wk = (const float*)d_in[1];
    const float* Wq = (const float*)d_in[2];
    const float* Wv = (const float*)d_in[3];
    float* out = (float*)d_out;

    // ws layout (bytes), total 14.25 MB:
    //   WF @0 (576KB) | KF @1MB (2MB) | QF @3MB (2MB) | VF @5MB (1MB)
    //   pm @6MB (128KB) | pl @6.125MB (128KB) | po @6.25MB (8MB)
    char* ws = (char*)d_ws;
    const size_t MB = 1024 * 1024;
    _Float16* WF = (_Float16*)(ws + 0 * MB);
    _Float16* KF = (_Float16*)(ws + 1 * MB);
    _Float16* QF = (_Float16*)(ws + 3 * MB);
    _Float16* VF = (_Float16*)(ws + 5 * MB);
    float* pm = (float*)(ws + 6 * MB);
    float* pl = (float*)(ws + 6 * MB + 128 * 1024);
    float* po = (float*)(ws + 6 * MB + 256 * 1024);

    wconvert_kernel<<<288, 64, 0, stream>>>(Wk, Wq, Wv, WF);

    proj_kernel<<<256, 64, 0, stream>>>(tokens, WF, KF, QF, VF);

    attn_mfma_kernel<<<128 * NSPLIT, 512, 0, stream>>>(QF, KF, VF, pm, pl, po);

    combine_kernel<<<T_TOK * H_DIM / 4 / 256, 256, 0, stream>>>(pm, pl, po, out);
}

// Round 3
// 136.088 us; speedup vs baseline: 1.1075x; 1.1075x over previous
//
#include <hip/hip_runtime.h>
#include <math.h>

#define T_TOK 8192
#define C_DIM 768
#define H_DIM 64
// reference MULTIPLIES by c**0.5; we work in exp2 domain: scale * log2(e)
#define SCALE_LOG2E (27.712812921102035f * 1.4426950408889634f)
#define NSPLIT 4

typedef _Float16 half8 __attribute__((ext_vector_type(8)));
typedef float floatx4 __attribute__((ext_vector_type(4)));

#define MFMA16(a, b, c) __builtin_amdgcn_mfma_f32_16x16x32_f16(a, b, c, 0, 0, 0)
// wait lgkmcnt(0) only: vmcnt=0x3F, expcnt=7, lgkm=0
#define WAIT_LGKM0() __builtin_amdgcn_s_waitcnt(0xC07F)
#define EXP2F(x) __builtin_amdgcn_exp2f(x)

// global_load_lds: width 16B/lane; LDS dest = wave-uniform base + lane*16 (HW),
// global src = per-lane address (we pass base + lane*8 f16 = lane*16 B).
typedef __attribute__((address_space(3))) void lds_void;
typedef const __attribute__((address_space(1))) void gbl_void;
#define GLOAD16(gp, lp) \
    __builtin_amdgcn_global_load_lds((gbl_void*)(gp), (lds_void*)(lp), 16, 0, 0)

template <int K> struct IC { static constexpr int v = K; };

// Fragment layouts in workspace (all 1KB frags, perfectly coalesced b128/lane):
//   WF[mat][kt(24)][nb(4)][hl(2)][512 f16]   = W[kt*32+quad*8+j][nb*16+l15]
//   KF[t(128)][nb(4)][ks(2)][hl(2)][512 f16] = K[t*64+nb*16+l15][ks*32+quad*8+j]
//   QF[rb(512)][ks(2)][hl(2)][512 f16]       = Q[rb*16+l15][ks*32+quad*8+j]
//   VF[t(128)][nb(4)][ks(2)][512 f16]        = V[t*64+ks*32+quad*8+j][nb*16+l15]

// ---------------------------------------------------------------------------
// Kernel 0: W fp32 -> hi/lo f16 B-frags.  288 blocks x 64 threads.
// (byte-identical to the round-10 passing version)
// ---------------------------------------------------------------------------
__global__ __launch_bounds__(64) void wconvert_kernel(
    const float* __restrict__ Wk, const float* __restrict__ Wq,
    const float* __restrict__ Wv, _Float16* __restrict__ WF)
{
    const int b = blockIdx.x;                  // 3*24*4
    const int mat = b / 96, rem = b % 96, kt = rem >> 2, nb = rem & 3;
    const int lane = threadIdx.x & 63, l15 = lane & 15, quad = lane >> 4;
    const float* __restrict__ W = (mat == 0) ? Wk : (mat == 1) ? Wq : Wv;

    half8 h, l;
#pragma unroll
    for (int j = 0; j < 8; ++j) {
        const float v = W[(kt * 32 + quad * 8 + j) * H_DIM + nb * 16 + l15];
        const _Float16 hv = (_Float16)v;
        h[j] = hv;
        l[j] = (_Float16)(v - (float)hv);
    }
    _Float16* dst = WF + ((((size_t)mat * 24 + kt) * 4 + nb) * 2) * 512 + lane * 8;
    *(half8*)dst = h;
    *(half8*)(dst + 512) = l;
}

// ---------------------------------------------------------------------------
// Kernel 1: FUSED MFMA projection, W staged through LDS.
// Round-2 post-mortem: the token-FIFO refill was issued BEFORE the current
// slot was consumed -> region B read tile kt+4 instead of kt (absmax 7.16).
// Fix: snapshot x0..x3 = tf[slot] at the TOP of the iteration (register
// copy, no vmem op -> the vmcnt ledger below is unchanged), THEN issue the
// W(kt+1) DMA and the tf[slot] <- kt+4 refill.
// Wait discipline: counted vmcnt (never 0 in-loop), issue order pinned by
// sched_barrier(0) fences: [x snapshot][DMA W(kt+1)][tok refill kt+4]
// [s_waitcnt vmcnt(N)][convert + ds_read + 56 MFMA].  N = #vmem ops younger
// than the W(kt) DMA block:
//   kt=0: 16 tok-init + 20 W(1) + 4 tok(4) = 40;  kt=1..19: 4+20+4 = 28;
//   kt=20: 24;  kt=21,22: 20;  kt=23: 0.
// Steady-state queue after the wait: [tok(kt+3), W(kt+1), tok(kt+4)] = 28,
// so W(kt) is provably retired and the 4-deep HBM token FIFO stays in
// flight.  Numerics bit-identical to round 1 (same MFMA order per acc).
// ---------------------------------------------------------------------------
__global__ __launch_bounds__(64, 1) void proj_kernel(
    const float* __restrict__ tokens, const _Float16* __restrict__ WF,
    _Float16* __restrict__ KF, _Float16* __restrict__ QF,
    _Float16* __restrict__ VF)
{
    // W double buffer: 2 x 20 frags x 1KB = 40960 B.  Epilogue reuses it as
    // float Cb[3*32*68] (26112 B).
    __shared__ __align__(16) char smemraw[40960];
    const int b = blockIdx.x;                  // 256 blocks, 32 rows each
    const int lane = threadIdx.x & 63, l15 = lane & 15, quad = lane >> 4;
    const int row0 = b * 32;

    floatx4 acc[3][2][4];
#pragma unroll
    for (int mat = 0; mat < 3; ++mat)
#pragma unroll
        for (int mb = 0; mb < 2; ++mb)
#pragma unroll
            for (int nb = 0; nb < 4; ++nb) acc[mat][mb][nb] = 0;

    const float* __restrict__ xb0 = tokens + (size_t)(row0 + l15) * C_DIM + quad * 8;
    const float* __restrict__ xb1 = tokens + (size_t)(row0 + 16 + l15) * C_DIM + quad * 8;

    // LDS slot map within one 20KB buffer (f16 elem offsets, 512 per frag):
    //   K  hi/lo: (nb*2+hl)*512      (slots 0..7)
    //   Q  hi/lo: (8+nb*2+hl)*512    (slots 8..15)
    //   V  hi   : (16+nb)*512        (slots 16..19)
    // Global frag base (f16 elems): (((mat*24+kt)*4+nb)*2 + hl)*512 + lane*8.

    // ---- prologue: DMA W(0) into buf0, then fill the 4-deep token FIFO ----
    {
        _Float16* wb0 = (_Float16*)smemraw;
#pragma unroll
        for (int nb = 0; nb < 4; ++nb) {
            const _Float16* gK = WF + (size_t)((0 * 4 + nb) * 2) * 512 + lane * 8;
            const _Float16* gQ =
                WF + (size_t)(((1 * 24) * 4 + nb) * 2) * 512 + lane * 8;
            const _Float16* gV =
                WF + (size_t)(((2 * 24) * 4 + nb) * 2) * 512 + lane * 8;
            GLOAD16(gK,       wb0 + (nb * 2 + 0) * 512);
            GLOAD16(gK + 512, wb0 + (nb * 2 + 1) * 512);
            GLOAD16(gQ,       wb0 + (8 + nb * 2 + 0) * 512);
            GLOAD16(gQ + 512, wb0 + (8 + nb * 2 + 1) * 512);
            GLOAD16(gV,       wb0 + (16 + nb) * 512);
        }
    }
    __builtin_amdgcn_sched_barrier(0);
    float4 tf[4][4];
#pragma unroll
    for (int d = 0; d < 4; ++d) {
        tf[d][0] = *(const float4*)(xb0 + d * 32);
        tf[d][1] = *(const float4*)(xb0 + d * 32 + 4);
        tf[d][2] = *(const float4*)(xb1 + d * 32);
        tf[d][3] = *(const float4*)(xb1 + d * 32 + 4);
    }
    __builtin_amdgcn_sched_barrier(0);

    auto iter = [&](auto kc) {
        constexpr int kt = decltype(kc)::v;
        constexpr int slot = kt & 3;
        constexpr int curb = kt & 1;
        _Float16* wb  = (_Float16*)(smemraw + curb * 20480);
        _Float16* wbn = (_Float16*)(smemraw + (curb ^ 1) * 20480);

        // ---- region A0: snapshot CURRENT tokens before any refill ----
        __builtin_amdgcn_sched_barrier(0);
        const float4 x0 = tf[slot][0], x1 = tf[slot][1];
        const float4 x2 = tf[slot][2], x3 = tf[slot][3];
        __builtin_amdgcn_sched_barrier(0);

        // ---- region A1: DMA W(kt+1) into the other buffer ----
        if constexpr (kt < 23) {
            constexpr int ktn = kt + 1;
#pragma unroll
            for (int nb = 0; nb < 4; ++nb) {
                const _Float16* gK =
                    WF + (size_t)((ktn * 4 + nb) * 2) * 512 + lane * 8;
                const _Float16* gQ =
                    WF + (size_t)(((24 + ktn) * 4 + nb) * 2) * 512 + lane * 8;
                const _Float16* gV =
                    WF + (size_t)(((48 + ktn) * 4 + nb) * 2) * 512 + lane * 8;
                GLOAD16(gK,       wbn + (nb * 2 + 0) * 512);
                GLOAD16(gK + 512, wbn + (nb * 2 + 1) * 512);
                GLOAD16(gQ,       wbn + (8 + nb * 2 + 0) * 512);
                GLOAD16(gQ + 512, wbn + (8 + nb * 2 + 1) * 512);
                GLOAD16(gV,       wbn + (16 + nb) * 512);
            }
        }
        __builtin_amdgcn_sched_barrier(0);
        // ---- region A2: refill token FIFO slot with kt+4 ----
        if constexpr (kt + 4 < 24) {
            constexpr int ktf = kt + 4;
            tf[slot][0] = *(const float4*)(xb0 + ktf * 32);
            tf[slot][1] = *(const float4*)(xb0 + ktf * 32 + 4);
            tf[slot][2] = *(const float4*)(xb1 + ktf * 32);
            tf[slot][3] = *(const float4*)(xb1 + ktf * 32 + 4);
        }
        __builtin_amdgcn_sched_barrier(0);
        // ---- counted wait: W(kt) complete, token FIFO left in flight ----
        constexpr int VMN = (kt == 0)
            ? 40
            : ((kt <= 20 ? 4 : 0) + (kt <= 22 ? 20 : 0) + (kt <= 19 ? 4 : 0));
        asm volatile("s_waitcnt vmcnt(%0)" ::"n"(VMN));
        __builtin_amdgcn_sched_barrier(0);

        // ---- region B: convert A-tiles, ds_read W frags, 56 MFMA ----
        half8 ah[2], al[2];
        {
            const float xs0[8] = {x0.x, x0.y, x0.z, x0.w, x1.x, x1.y, x1.z, x1.w};
            const float xs1[8] = {x2.x, x2.y, x2.z, x2.w, x3.x, x3.y, x3.z, x3.w};
#pragma unroll
            for (int e = 0; e < 8; ++e) {
                _Float16 hv = (_Float16)xs0[e];
                ah[0][e] = hv;
                al[0][e] = (_Float16)(xs0[e] - (float)hv);
                hv = (_Float16)xs1[e];
                ah[1][e] = hv;
                al[1][e] = (_Float16)(xs1[e] - (float)hv);
            }
        }
        const _Float16* wp = wb + lane * 8;
#pragma unroll
        for (int nb = 0; nb < 4; ++nb) {
            const half8 kh = *(const half8*)(wp + (nb * 2 + 0) * 512);
            const half8 kl = *(const half8*)(wp + (nb * 2 + 1) * 512);
            const half8 qh = *(const half8*)(wp + (8 + nb * 2 + 0) * 512);
            const half8 ql = *(const half8*)(wp + (8 + nb * 2 + 1) * 512);
            const half8 vh = *(const half8*)(wp + (16 + nb) * 512);
#pragma unroll
            for (int mb = 0; mb < 2; ++mb) {
                acc[0][mb][nb] = MFMA16(ah[mb], kh, acc[0][mb][nb]);
                acc[0][mb][nb] = MFMA16(ah[mb], kl, acc[0][mb][nb]);
                acc[0][mb][nb] = MFMA16(al[mb], kh, acc[0][mb][nb]);
                acc[1][mb][nb] = MFMA16(ah[mb], qh, acc[1][mb][nb]);
                acc[1][mb][nb] = MFMA16(ah[mb], ql, acc[1][mb][nb]);
                acc[1][mb][nb] = MFMA16(al[mb], qh, acc[1][mb][nb]);
                acc[2][mb][nb] = MFMA16(ah[mb], vh, acc[2][mb][nb]);
            }
        }
    };
#define PITER(k) iter(IC<k>{});
    PITER(0)  PITER(1)  PITER(2)  PITER(3)  PITER(4)  PITER(5)
    PITER(6)  PITER(7)  PITER(8)  PITER(9)  PITER(10) PITER(11)
    PITER(12) PITER(13) PITER(14) PITER(15) PITER(16) PITER(17)
    PITER(18) PITER(19) PITER(20) PITER(21) PITER(22) PITER(23)
#undef PITER

    // Fence: last iteration's ds_reads (buf1, 20480..40960) must have
    // returned before Cb writes (0..26112, overlaps buf1's head) can land.
    __builtin_amdgcn_wave_barrier();
    WAIT_LGKM0();
    __builtin_amdgcn_wave_barrier();

    // ---- epilogue: reuse smemraw as float Cb[3*32*68] (stride 68) ----
    float* Cb = (float*)smemraw;
#pragma unroll
    for (int mat = 0; mat < 3; ++mat)
#pragma unroll
        for (int mb = 0; mb < 2; ++mb)
#pragma unroll
            for (int nb = 0; nb < 4; ++nb)
#pragma unroll
                for (int r = 0; r < 4; ++r)
                    Cb[mat * 2176 + (mb * 16 + quad * 4 + r) * 68 + nb * 16 + l15] =
                        acc[mat][mb][nb][r];
    __builtin_amdgcn_wave_barrier();
    WAIT_LGKM0();
    __builtin_amdgcn_wave_barrier();

    // K (mat 0) and Q (mat 1) epilogues: hi/lo frag writes
#pragma unroll
    for (int nbL = 0; nbL < 2; ++nbL) {
#pragma unroll
        for (int ks = 0; ks < 2; ++ks) {
            // ---- K ----
            {
                const float* cp = Cb + (nbL * 16 + l15) * 68 + ks * 32 + quad * 8;
                const float4 c0 = *(const float4*)cp;
                const float4 c1 = *(const float4*)(cp + 4);
                const float cs[8] = {c0.x, c0.y, c0.z, c0.w, c1.x, c1.y, c1.z, c1.w};
                half8 h, l;
#pragma unroll
                for (int e = 0; e < 8; ++e) {
                    const _Float16 hv = (_Float16)cs[e];
                    h[e] = hv;
                    l[e] = (_Float16)(cs[e] - (float)hv);
                }
                const int t = b >> 1, nb = (b & 1) * 2 + nbL;
                _Float16* dst =
                    KF + (((size_t)(t * 4 + nb) * 2 + ks) * 2) * 512 + lane * 8;
                *(half8*)dst = h;
                *(half8*)(dst + 512) = l;
            }
            // ---- Q ----
            {
                const float* cp =
                    Cb + 2176 + (nbL * 16 + l15) * 68 + ks * 32 + quad * 8;
                const float4 c0 = *(const float4*)cp;
                const float4 c1 = *(const float4*)(cp + 4);
                const float cs[8] = {c0.x, c0.y, c0.z, c0.w, c1.x, c1.y, c1.z, c1.w};
                half8 h, l;
#pragma unroll
                for (int e = 0; e < 8; ++e) {
                    const _Float16 hv = (_Float16)cs[e];
                    h[e] = hv;
                    l[e] = (_Float16)(cs[e] - (float)hv);
                }
                const int rb = b * 2 + nbL;
                _Float16* dst = QF + (((size_t)rb * 2 + ks) * 2) * 512 + lane * 8;
                *(half8*)dst = h;
                *(half8*)(dst + 512) = l;
            }
        }
    }

    // V (mat 2) epilogue: rows b*32..b*32+31 == token tile t = b>>1, ks = b&1
    {
        const int t = b >> 1, ks = b & 1;
#pragma unroll
        for (int nb = 0; nb < 4; ++nb) {
            half8 h;
#pragma unroll
            for (int j = 0; j < 8; ++j)
                h[j] = (_Float16)Cb[2 * 2176 + (quad * 8 + j) * 68 + nb * 16 + l15];
            *(half8*)(VF + ((size_t)(t * 4 + nb) * 2 + ks) * 512 + lane * 8) = h;
        }
    }
}

// ---------------------------------------------------------------------------
// Kernel 2: causal flash attention.
// (byte-identical to the round-10 passing version)
// ---------------------------------------------------------------------------
__global__ __launch_bounds__(512, 2) void attn_mfma_kernel(
    const _Float16* __restrict__ QF, const _Float16* __restrict__ KF,
    const _Float16* __restrict__ VF,
    float* __restrict__ pm, float* __restrict__ pl, float* __restrict__ po)
{
    // Ps: [w(8)][mb(2)][16 rows][stride 72 f16] = 36864 B (9216 floats).
    // Merge phase reuses the same region:
    //   mO: [slot(2)][mhalf(2)][32][64] floats  @ 0     (8192 floats)
    //   mM: [slot(2)][mhalf(2)][32]             @ 8192  (128 floats)
    //   mL: [slot(2)][mhalf(2)][32]             @ 8320  (128 floats)
    __shared__ __align__(16) float smemf[9216];
    _Float16* Ps = (_Float16*)smemf;

    const int w = threadIdx.x >> 6, lane = threadIdx.x & 63;
    const int l15 = lane & 15, quad = lane >> 4;
    const int mhalf = w & 1, ss = w >> 1;

    const int b = blockIdx.x;
    const int j = b & 255, hb = b >> 8;
    const int qt = (hb == 0) ? (j >> 1) : (127 - (j >> 1));
    const int sp = (hb << 1) | (j & 1);

    const int qbase = qt * 64;
    const int wrow0 = qbase + mhalf * 32;

    // Q A-frags (hi/lo), loaded once
    half8 qh[2][2], ql[2][2];
#pragma unroll
    for (int mb = 0; mb < 2; ++mb)
#pragma unroll
        for (int ks = 0; ks < 2; ++ks) {
            const int rb = qt * 4 + mhalf * 2 + mb;
            const _Float16* qp = QF + (((size_t)rb * 2 + ks) * 2) * 512 + lane * 8;
            qh[mb][ks] = *(const half8*)qp;
            ql[mb][ks] = *(const half8*)(qp + 512);
        }

    floatx4 O[2][4];
#pragma unroll
    for (int mb = 0; mb < 2; ++mb)
#pragma unroll
        for (int nb = 0; nb < 4; ++nb) O[mb][nb] = 0;
    float mreg[2][4], lreg[2][4];
#pragma unroll
    for (int mb = 0; mb < 2; ++mb)
#pragma unroll
        for (int r = 0; r < 4; ++r) { mreg[mb][r] = -INFINITY; lreg[mb][r] = 0.f; }

    const int t0 = sp + 4 * ss;
    half8 bh[4][2], bl[4][2];
    if (t0 <= qt) {                            // preload first tile's K frags
#pragma unroll
        for (int nb = 0; nb < 4; ++nb)
#pragma unroll
            for (int ks = 0; ks < 2; ++ks) {
                const _Float16* kp =
                    KF + (((size_t)(t0 * 4 + nb) * 2 + ks) * 2) * 512 + lane * 8;
                bh[nb][ks] = *(const half8*)kp;
                bl[nb][ks] = *(const half8*)(kp + 512);
            }
    }

    for (int t = t0; t <= qt; t += 16) {
        const int kb = t * 64;

        // V frags of THIS tile: issued ~600cy before their PV use
        half8 v0r[4], v1r[4];
#pragma unroll
        for (int nb = 0; nb < 4; ++nb) {
            const _Float16* vp = VF + ((size_t)(t * 4 + nb) * 2) * 512 + lane * 8;
            v0r[nb] = *(const half8*)vp;
            v1r[nb] = *(const half8*)(vp + 512);
        }

        // S = Q K^T (hi*hi + hi*lo + lo*hi), scaled into exp2 domain
        float sv[2][4][4];
#pragma unroll
        for (int mb = 0; mb < 2; ++mb)
#pragma unroll
            for (int nb = 0; nb < 4; ++nb) {
                floatx4 s = 0;
#pragma unroll
                for (int ks = 0; ks < 2; ++ks) {
                    s = MFMA16(qh[mb][ks], bh[nb][ks], s);
                    s = MFMA16(qh[mb][ks], bl[nb][ks], s);
                    s = MFMA16(ql[mb][ks], bh[nb][ks], s);
                }
#pragma unroll
                for (int r = 0; r < 4; ++r) sv[mb][nb][r] = s[r] * SCALE_LOG2E;
            }

        // prefetch NEXT tile's K frags (current ones are dead after S)
        if (t + 16 <= qt) {
            const int tn = t + 16;
#pragma unroll
            for (int nb = 0; nb < 4; ++nb)
#pragma unroll
                for (int ks = 0; ks < 2; ++ks) {
                    const _Float16* kp =
                        KF + (((size_t)(tn * 4 + nb) * 2 + ks) * 2) * 512 + lane * 8;
                    bh[nb][ks] = *(const half8*)kp;
                    bl[nb][ks] = *(const half8*)(kp + 512);
                }
        }

        if (kb + 63 > wrow0) {                 // diagonal tile: causal mask
#pragma unroll
            for (int mb = 0; mb < 2; ++mb) {
                const int rowbase = wrow0 + mb * 16 + quad * 4;
#pragma unroll
                for (int nb = 0; nb < 4; ++nb) {
                    const int col = kb + nb * 16 + l15;
#pragma unroll
                    for (int r = 0; r < 4; ++r)
                        if (col > rowbase + r) sv[mb][nb][r] = -INFINITY;
                }
            }
        }

        // online softmax (exp2 domain)
#pragma unroll
        for (int mb = 0; mb < 2; ++mb) {
#pragma unroll
            for (int r = 0; r < 4; ++r) {
                float rm = fmaxf(fmaxf(sv[mb][0][r], sv[mb][1][r]),
                                 fmaxf(sv[mb][2][r], sv[mb][3][r]));
                rm = fmaxf(rm, __shfl_xor(rm, 1));
                rm = fmaxf(rm, __shfl_xor(rm, 2));
                rm = fmaxf(rm, __shfl_xor(rm, 4));
                rm = fmaxf(rm, __shfl_xor(rm, 8));
                const float mnew = fmaxf(mreg[mb][r], rm);
                const float alpha = EXP2F(mreg[mb][r] - mnew);   // -inf -> 0
                float psum = 0.f;
#pragma unroll
                for (int nb = 0; nb < 4; ++nb) {
                    const float p = EXP2F(sv[mb][nb][r] - mnew);  // -inf -> 0
                    psum += p;
                    Ps[(w * 2 + mb) * 1152 + (quad * 4 + r) * 72 + nb * 16 + l15] =
                        (_Float16)p;
                }
                lreg[mb][r] = lreg[mb][r] * alpha + psum;
                mreg[mb][r] = mnew;
#pragma unroll
                for (int nb = 0; nb < 4; ++nb) O[mb][nb][r] *= alpha;
            }
        }

        // P: C-layout -> A-layout via wave-private LDS
        __builtin_amdgcn_wave_barrier();
        WAIT_LGKM0();
        __builtin_amdgcn_wave_barrier();
        half8 pa0[2], pa1[2];
#pragma unroll
        for (int mb = 0; mb < 2; ++mb) {
            const _Float16* pp = Ps + (w * 2 + mb) * 1152 + l15 * 72 + quad * 8;
            pa0[mb] = *(const half8*)pp;
            pa1[mb] = *(const half8*)(pp + 32);
        }

        // PV with the V frags loaded at tile top
#pragma unroll
        for (int nb = 0; nb < 4; ++nb) {
#pragma unroll
            for (int mb = 0; mb < 2; ++mb) {
                O[mb][nb] = MFMA16(pa0[mb], v0r[nb], O[mb][nb]);
                O[mb][nb] = MFMA16(pa1[mb], v1r[nb], O[mb][nb]);
            }
        }
        __builtin_amdgcn_wave_barrier();
    }

    // row-sum l across the 16-lane group (lane-local partials are exact
    // because alpha factors are row-uniform)
#pragma unroll
    for (int mb = 0; mb < 2; ++mb)
#pragma unroll
        for (int r = 0; r < 4; ++r) {
            float s = lreg[mb][r];
            s += __shfl_xor(s, 1);
            s += __shfl_xor(s, 2);
            s += __shfl_xor(s, 4);
            s += __shfl_xor(s, 8);
            lreg[mb][r] = s;
        }

    // ---- 2-round subsplit merge (proven pattern applied twice) ----
    __syncthreads();                           // Ps now dead; reuse as buffers
    // Round A: ss in {2,3} publish to slot ss-2
    if (ss >= 2) {
        const int slot = ss - 2;
#pragma unroll
        for (int mb = 0; mb < 2; ++mb)
#pragma unroll
            for (int r = 0; r < 4; ++r) {
                const int row32 = mb * 16 + quad * 4 + r;
                const int sidx = (slot * 2 + mhalf) * 32 + row32;
#pragma unroll
                for (int nb = 0; nb < 4; ++nb)
                    smemf[sidx * 64 + nb * 16 + l15] = O[mb][nb][r];
                if (l15 == 0) {
                    smemf[8192 + sidx] = mreg[mb][r];
                    smemf[8320 + sidx] = lreg[mb][r];
                }
            }
    }
    __syncthreads();
    if (ss < 2) {                              // ss0 <- slot0(ss2), ss1 <- slot1(ss3)
        const int slot = ss;
#pragma unroll
        for (int mb = 0; mb < 2; ++mb)
#pragma unroll
            for (int r = 0; r < 4; ++r) {
                const int row32 = mb * 16 + quad * 4 + r;
                const int sidx = (slot * 2 + mhalf) * 32 + row32;
                const float m1 = mreg[mb][r], l1 = lreg[mb][r];
                const float m2 = smemf[8192 + sidx];
                const float l2 = smemf[8320 + sidx];
                const float mm = fmaxf(m1, m2);
                const float a1 = (m1 == -INFINITY) ? 0.f : EXP2F(m1 - mm);
                const float a2 = (m2 == -INFINITY) ? 0.f : EXP2F(m2 - mm);
#pragma unroll
                for (int nb = 0; nb < 4; ++nb)
                    O[mb][nb][r] = O[mb][nb][r] * a1 +
                                   smemf[sidx * 64 + nb * 16 + l15] * a2;
                mreg[mb][r] = mm;
                lreg[mb][r] = l1 * a1 + l2 * a2;
            }
    }
    __syncthreads();
    // Round B: ss==1 publish merged state to slot 0
    if (ss == 1) {
#pragma unroll
        for (int mb = 0; mb < 2; ++mb)
#pragma unroll
            for (int r = 0; r < 4; ++r) {
                const int row32 = mb * 16 + quad * 4 + r;
                const int sidx = mhalf * 32 + row32;   // slot 0
#pragma unroll
                for (int nb = 0; nb < 4; ++nb)
                    smemf[sidx * 64 + nb * 16 + l15] = O[mb][nb][r];
                if (l15 == 0) {
                    smemf[8192 + sidx] = mreg[mb][r];
                    smemf[8320 + sidx] = lreg[mb][r];
                }
            }
    }
    __syncthreads();
    if (ss == 0) {                             // final merge + write partials
        const int pidx = qt * NSPLIT + sp;
#pragma unroll
        for (int mb = 0; mb < 2; ++mb)
#pragma unroll
            for (int r = 0; r < 4; ++r) {
                const int row32 = mb * 16 + quad * 4 + r;
                const int sidx = mhalf * 32 + row32;   // slot 0
                const float m1 = mreg[mb][r], l1 = lreg[mb][r];
                const float m2 = smemf[8192 + sidx];
                const float l2 = smemf[8320 + sidx];
                const float mm = fmaxf(m1, m2);
                const float a1 = (m1 == -INFINITY) ? 0.f : EXP2F(m1 - mm);
                const float a2 = (m2 == -INFINITY) ? 0.f : EXP2F(m2 - mm);
                const int row = mhalf * 32 + row32;
                float* dst = po + ((size_t)pidx * 64 + row) * 64;
#pragma unroll
                for (int nb = 0; nb < 4; ++nb)
                    dst[nb * 16 + l15] =
                        O[mb][nb][r] * a1 + smemf[sidx * 64 + nb * 16 + l15] * a2;
                if (l15 == 0) {
                    pm[pidx * 64 + row] = mm;
                    pl[pidx * 64 + row] = l1 * a1 + l2 * a2;
                }
            }
    }
}

// ---------------------------------------------------------------------------
// Kernel 3: merge the NSPLIT split-partials per row (exp2 domain).
// (byte-identical to the round-11 passing float4 version)
// ---------------------------------------------------------------------------
__global__ __launch_bounds__(256) void combine_kernel(
    const float* __restrict__ pm, const float* __restrict__ pl,
    const float* __restrict__ po, float* __restrict__ out)
{
    const int vid = blockIdx.x * 256 + threadIdx.x;    // over T*H/4
    const int row = vid >> 4;                          // 16 float4 per row
    const int d4  = vid & 15;
    const int qt  = row >> 6;
    const int r   = row & 63;

    float mm = -INFINITY;
#pragma unroll
    for (int s = 0; s < NSPLIT; ++s)
        mm = fmaxf(mm, pm[(qt * NSPLIT + s) * 64 + r]);
    float L = 0.f;
    float4 val = make_float4(0.f, 0.f, 0.f, 0.f);
#pragma unroll
    for (int s = 0; s < NSPLIT; ++s) {
        const int p = (qt * NSPLIT + s) * 64 + r;
        const float mp = pm[p];
        const float sc = (mp > -INFINITY) ? EXP2F(mp - mm) : 0.f;
        L += pl[p] * sc;
        const float4 v = *(const float4*)(po + (size_t)p * H_DIM + d4 * 4);
        val.x += v.x * sc; val.y += v.y * sc;
        val.z += v.z * sc; val.w += v.w * sc;
    }
    const float inv = 1.0f / L;
    float4 o; o.x = val.x * inv; o.y = val.y * inv;
    o.z = val.z * inv; o.w = val.w * inv;
    *(float4*)(out + (size_t)row * H_DIM + d4 * 4) = o;
}

// ---------------------------------------------------------------------------
extern "C" void kernel_launch(void* const* d_in, const int* in_sizes, int n_in,
                              void* d_out, int out_size, void* d_ws, size_t ws_size,
                              hipStream_t stream)
{
    const float* tokens = (const float*)d_in[0];
    const float* Wk = (const float*)d_in[1];
    const float* Wq = (const float*)d_in[2];
    const float* Wv = (const float*)d_in[3];
    float* out = (float*)d_out;

    // ws layout (bytes), total 14.25 MB:
    //   WF @0 (576KB) | KF @1MB (2MB) | QF @3MB (2MB) | VF @5MB (1MB)
    //   pm @6MB (128KB) | pl @6.125MB (128KB) | po @6.25MB (8MB)
    char* ws = (char*)d_ws;
    const size_t MB = 1024 * 1024;
    _Float16* WF = (_Float16*)(ws + 0 * MB);
    _Float16* KF = (_Float16*)(ws + 1 * MB);
    _Float16* QF = (_Float16*)(ws + 3 * MB);
    _Float16* VF = (_Float16*)(ws + 5 * MB);
    float* pm = (float*)(ws + 6 * MB);
    float* pl = (float*)(ws + 6 * MB + 128 * 1024);
    float* po = (float*)(ws + 6 * MB + 256 * 1024);

    wconvert_kernel<<<288, 64, 0, stream>>>(Wk, Wq, Wv, WF);

    proj_kernel<<<256, 64, 0, stream>>>(tokens, WF, KF, QF, VF);

    attn_mfma_kernel<<<128 * NSPLIT, 512, 0, stream>>>(QF, KF, VF, pm, pl, po);

    combine_kernel<<<T_TOK * H_DIM / 4 / 256, 256, 0, stream>>>(pm, pl, po, out);
}

// Round 5
// 125.845 us; speedup vs baseline: 1.1977x; 1.0814x over previous
//
#include <hip/hip_runtime.h>
#include <math.h>

#define T_TOK 8192
#define C_DIM 768
#define H_DIM 64
// reference MULTIPLIES by c**0.5; we work in exp2 domain: scale * log2(e)
#define SCALE_LOG2E (27.712812921102035f * 1.4426950408889634f)
#define NSPLIT 4

typedef _Float16 half8 __attribute__((ext_vector_type(8)));
typedef float floatx4 __attribute__((ext_vector_type(4)));

#define MFMA16(a, b, c) __builtin_amdgcn_mfma_f32_16x16x32_f16(a, b, c, 0, 0, 0)
// wait lgkmcnt(0) only: vmcnt=0x3F, expcnt=7, lgkm=0
#define WAIT_LGKM0() __builtin_amdgcn_s_waitcnt(0xC07F)
#define EXP2F(x) __builtin_amdgcn_exp2f(x)

// global_load_lds: width 16B/lane; LDS dest = wave-uniform base + lane*16 (HW),
// global src = per-lane address (we pass base + lane*8 f16 = lane*16 B).
typedef __attribute__((address_space(3))) void lds_void;
typedef const __attribute__((address_space(1))) void gbl_void;
#define GLOAD16(gp, lp) \
    __builtin_amdgcn_global_load_lds((gbl_void*)(gp), (lds_void*)(lp), 16, 0, 0)

template <int K> struct IC { static constexpr int v = K; };

// Fragment layouts in workspace (all 1KB frags, perfectly coalesced b128/lane):
//   WF[mat][kt(24)][nb(4)][hl(2)][512 f16]   = W[kt*32+quad*8+j][nb*16+l15]
//   KF[t(128)][nb(4)][ks(2)][hl(2)][512 f16] = K[t*64+nb*16+l15][ks*32+quad*8+j]
//   QF[rb(512)][ks(2)][hl(2)][512 f16]       = Q[rb*16+l15][ks*32+quad*8+j]
//   VF[t(128)][nb(4)][ks(2)][512 f16]        = V[t*64+ks*32+quad*8+j][nb*16+l15]

// ---------------------------------------------------------------------------
// Kernel 0: W fp32 -> hi/lo f16 B-frags.  288 blocks x 64 threads.
// (byte-identical to the round-10 passing version)
// ---------------------------------------------------------------------------
__global__ __launch_bounds__(64) void wconvert_kernel(
    const float* __restrict__ Wk, const float* __restrict__ Wq,
    const float* __restrict__ Wv, _Float16* __restrict__ WF)
{
    const int b = blockIdx.x;                  // 3*24*4
    const int mat = b / 96, rem = b % 96, kt = rem >> 2, nb = rem & 3;
    const int lane = threadIdx.x & 63, l15 = lane & 15, quad = lane >> 4;
    const float* __restrict__ W = (mat == 0) ? Wk : (mat == 1) ? Wq : Wv;

    half8 h, l;
#pragma unroll
    for (int j = 0; j < 8; ++j) {
        const float v = W[(kt * 32 + quad * 8 + j) * H_DIM + nb * 16 + l15];
        const _Float16 hv = (_Float16)v;
        h[j] = hv;
        l[j] = (_Float16)(v - (float)hv);
    }
    _Float16* dst = WF + ((((size_t)mat * 24 + kt) * 4 + nb) * 2) * 512 + lane * 8;
    *(half8*)dst = h;
    *(half8*)(dst + 512) = l;
}

// ---------------------------------------------------------------------------
// Kernel 1: FUSED MFMA projection, W staged through LDS, SPLIT-K x2.
// (identical to the round-4 submission — that bench never ran: container
// acquisition failed twice, so this is an infra resubmit, not a new theory)
// 2 waves per block (128 thr).  Wave w owns kt in [12w, 12w+12) with its
// OWN 2x20KB W double buffer (80KB LDS, 1 block/CU) and its own 4-deep
// token FIFO over its half of the columns.  Per-wave serial chain halves;
// 2 SIMDs/CU active instead of 1.
// vmcnt ledger per wave (12 iters, in-order retirement proof as round 3):
//   ktl=0: 16 tok-init + 20 W(1) + 4 tok(4) = 40
//   ktl 1..7: tok(ktl+3) 4 + W(ktl+1) 20 + tok(ktl+4) 4 = 28
//   ktl=8: tok(11) 4 + W(9) 20 = 24;  ktl=9,10: W(ktl+1) 20;  ktl=11: 0.
// Merge: fp32 partials to disjoint Cb regions (Cb1 aliases wave-dbuf space
// -> __syncthreads fences), epilogue sums Cb0+Cb1; output work split by
// wave (K/Q: nbL=w; V: nb in {2w,2w+1}).  Numerics: one fp32 partial-sum
// split per accumulator (<=1 ulp, invisible at f16 output granularity).
// ---------------------------------------------------------------------------
__global__ __launch_bounds__(128, 1) void proj_kernel(
    const float* __restrict__ tokens, const _Float16* __restrict__ WF,
    _Float16* __restrict__ KF, _Float16* __restrict__ QF,
    _Float16* __restrict__ VF)
{
    // W dbufs: wave0 [0,40960), wave1 [40960,81920).
    // Epilogue reuse: Cb0 @0 (26112 B), Cb1 @26112 (26112 B).
    __shared__ __align__(16) char smemraw[81920];
    const int b = blockIdx.x;                  // 256 blocks, 32 rows each
    const int tid = threadIdx.x;
    const int w = tid >> 6;                    // wave id 0/1 (kt-split)
    const int lane = tid & 63, l15 = lane & 15, quad = lane >> 4;
    const int row0 = b * 32;
    const int kt0 = w * 12;                    // this wave's first kt

    floatx4 acc[3][2][4];
#pragma unroll
    for (int mat = 0; mat < 3; ++mat)
#pragma unroll
        for (int mb = 0; mb < 2; ++mb)
#pragma unroll
            for (int nb = 0; nb < 4; ++nb) acc[mat][mb][nb] = 0;

    // this wave's token columns: [kt0*32, kt0*32 + 384)
    const float* __restrict__ xb0 =
        tokens + (size_t)(row0 + l15) * C_DIM + kt0 * 32 + quad * 8;
    const float* __restrict__ xb1 =
        tokens + (size_t)(row0 + 16 + l15) * C_DIM + kt0 * 32 + quad * 8;

    _Float16* const wavebuf = (_Float16*)(smemraw + w * 40960);

    // LDS slot map within one 20KB buffer (f16 elem offsets, 512 per frag):
    //   K  hi/lo: (nb*2+hl)*512      (slots 0..7)
    //   Q  hi/lo: (8+nb*2+hl)*512    (slots 8..15)
    //   V  hi   : (16+nb)*512        (slots 16..19)
    // Global frag base (f16 elems): (((mat*24+kt)*4+nb)*2 + hl)*512 + lane*8.

    // ---- prologue: DMA W(kt0) into slot 0, then fill 4-deep token FIFO ----
    {
#pragma unroll
        for (int nb = 0; nb < 4; ++nb) {
            const _Float16* gK =
                WF + (size_t)((kt0 * 4 + nb) * 2) * 512 + lane * 8;
            const _Float16* gQ =
                WF + (size_t)(((24 + kt0) * 4 + nb) * 2) * 512 + lane * 8;
            const _Float16* gV =
                WF + (size_t)(((48 + kt0) * 4 + nb) * 2) * 512 + lane * 8;
            GLOAD16(gK,       wavebuf + (nb * 2 + 0) * 512);
            GLOAD16(gK + 512, wavebuf + (nb * 2 + 1) * 512);
            GLOAD16(gQ,       wavebuf + (8 + nb * 2 + 0) * 512);
            GLOAD16(gQ + 512, wavebuf + (8 + nb * 2 + 1) * 512);
            GLOAD16(gV,       wavebuf + (16 + nb) * 512);
        }
    }
    __builtin_amdgcn_sched_barrier(0);
    float4 tf[4][4];
#pragma unroll
    for (int d = 0; d < 4; ++d) {
        tf[d][0] = *(const float4*)(xb0 + d * 32);
        tf[d][1] = *(const float4*)(xb0 + d * 32 + 4);
        tf[d][2] = *(const float4*)(xb1 + d * 32);
        tf[d][3] = *(const float4*)(xb1 + d * 32 + 4);
    }
    __builtin_amdgcn_sched_barrier(0);

    auto iter = [&](auto kc) {
        constexpr int ktl = decltype(kc)::v;   // local kt 0..11
        constexpr int slot = ktl & 3;
        constexpr int curb = ktl & 1;
        _Float16* wb  = wavebuf + curb * 10240;        // 20480 B = 10240 f16
        _Float16* wbn = wavebuf + (curb ^ 1) * 10240;

        // ---- region A0: snapshot CURRENT tokens before any refill ----
        __builtin_amdgcn_sched_barrier(0);
        const float4 x0 = tf[slot][0], x1 = tf[slot][1];
        const float4 x2 = tf[slot][2], x3 = tf[slot][3];
        __builtin_amdgcn_sched_barrier(0);

        // ---- region A1: DMA W(kt0+ktl+1) into the other buffer ----
        if constexpr (ktl < 11) {
            const int ktn = kt0 + ktl + 1;
#pragma unroll
            for (int nb = 0; nb < 4; ++nb) {
                const _Float16* gK =
                    WF + (size_t)((ktn * 4 + nb) * 2) * 512 + lane * 8;
                const _Float16* gQ =
                    WF + (size_t)(((24 + ktn) * 4 + nb) * 2) * 512 + lane * 8;
                const _Float16* gV =
                    WF + (size_t)(((48 + ktn) * 4 + nb) * 2) * 512 + lane * 8;
                GLOAD16(gK,       wbn + (nb * 2 + 0) * 512);
                GLOAD16(gK + 512, wbn + (nb * 2 + 1) * 512);
                GLOAD16(gQ,       wbn + (8 + nb * 2 + 0) * 512);
                GLOAD16(gQ + 512, wbn + (8 + nb * 2 + 1) * 512);
                GLOAD16(gV,       wbn + (16 + nb) * 512);
            }
        }
        __builtin_amdgcn_sched_barrier(0);
        // ---- region A2: refill token FIFO slot with ktl+4 ----
        if constexpr (ktl + 4 < 12) {
            constexpr int ktf = ktl + 4;
            tf[slot][0] = *(const float4*)(xb0 + ktf * 32);
            tf[slot][1] = *(const float4*)(xb0 + ktf * 32 + 4);
            tf[slot][2] = *(const float4*)(xb1 + ktf * 32);
            tf[slot][3] = *(const float4*)(xb1 + ktf * 32 + 4);
        }
        __builtin_amdgcn_sched_barrier(0);
        // ---- counted wait: W(kt0+ktl) complete, token FIFO in flight ----
        constexpr int VMN = (ktl == 0)
            ? 40
            : ((ktl <= 8 ? 4 : 0) + (ktl <= 10 ? 20 : 0) + (ktl <= 7 ? 4 : 0));
        asm volatile("s_waitcnt vmcnt(%0)" ::"n"(VMN));
        __builtin_amdgcn_sched_barrier(0);

        // ---- region B: convert A-tiles, ds_read W frags, 56 MFMA ----
        half8 ah[2], al[2];
        {
            const float xs0[8] = {x0.x, x0.y, x0.z, x0.w, x1.x, x1.y, x1.z, x1.w};
            const float xs1[8] = {x2.x, x2.y, x2.z, x2.w, x3.x, x3.y, x3.z, x3.w};
#pragma unroll
            for (int e = 0; e < 8; ++e) {
                _Float16 hv = (_Float16)xs0[e];
                ah[0][e] = hv;
                al[0][e] = (_Float16)(xs0[e] - (float)hv);
                hv = (_Float16)xs1[e];
                ah[1][e] = hv;
                al[1][e] = (_Float16)(xs1[e] - (float)hv);
            }
        }
        const _Float16* wp = wb + lane * 8;
#pragma unroll
        for (int nb = 0; nb < 4; ++nb) {
            const half8 kh = *(const half8*)(wp + (nb * 2 + 0) * 512);
            const half8 kl = *(const half8*)(wp + (nb * 2 + 1) * 512);
            const half8 qh = *(const half8*)(wp + (8 + nb * 2 + 0) * 512);
            const half8 ql = *(const half8*)(wp + (8 + nb * 2 + 1) * 512);
            const half8 vh = *(const half8*)(wp + (16 + nb) * 512);
#pragma unroll
            for (int mb = 0; mb < 2; ++mb) {
                acc[0][mb][nb] = MFMA16(ah[mb], kh, acc[0][mb][nb]);
                acc[0][mb][nb] = MFMA16(ah[mb], kl, acc[0][mb][nb]);
                acc[0][mb][nb] = MFMA16(al[mb], kh, acc[0][mb][nb]);
                acc[1][mb][nb] = MFMA16(ah[mb], qh, acc[1][mb][nb]);
                acc[1][mb][nb] = MFMA16(ah[mb], ql, acc[1][mb][nb]);
                acc[1][mb][nb] = MFMA16(al[mb], qh, acc[1][mb][nb]);
                acc[2][mb][nb] = MFMA16(ah[mb], vh, acc[2][mb][nb]);
            }
        }
    };
#define PITER(k) iter(IC<k>{});
    PITER(0)  PITER(1)  PITER(2)  PITER(3)  PITER(4)  PITER(5)
    PITER(6)  PITER(7)  PITER(8)  PITER(9)  PITER(10) PITER(11)
#undef PITER

    // Both waves done (drains all vm/lgkm) before Cb regions (which alias
    // the other wave's W dbuf space) are written.
    __syncthreads();

    // ---- wave-private fp32 partials into disjoint Cb regions ----
    float* Cb0 = (float*)smemraw;              // wave0 partial
    float* Cb1 = (float*)(smemraw + 26112);    // wave1 partial
    float* Cbw = w ? Cb1 : Cb0;
#pragma unroll
    for (int mat = 0; mat < 3; ++mat)
#pragma unroll
        for (int mb = 0; mb < 2; ++mb)
#pragma unroll
            for (int nb = 0; nb < 4; ++nb)
#pragma unroll
                for (int r = 0; r < 4; ++r)
                    Cbw[mat * 2176 + (mb * 16 + quad * 4 + r) * 68 + nb * 16 + l15] =
                        acc[mat][mb][nb][r];
    __syncthreads();

    // ---- merged epilogue (element = Cb0 + Cb1), work split by wave ----
    // K (mat 0) and Q (mat 1): wave w handles nbL = w.
    {
        const int nbL = w;
#pragma unroll
        for (int ks = 0; ks < 2; ++ks) {
            // ---- K ----
            {
                const int off = (nbL * 16 + l15) * 68 + ks * 32 + quad * 8;
                const float4 a0 = *(const float4*)(Cb0 + off);
                const float4 a1 = *(const float4*)(Cb0 + off + 4);
                const float4 b0 = *(const float4*)(Cb1 + off);
                const float4 b1 = *(const float4*)(Cb1 + off + 4);
                const float cs[8] = {a0.x + b0.x, a0.y + b0.y, a0.z + b0.z,
                                     a0.w + b0.w, a1.x + b1.x, a1.y + b1.y,
                                     a1.z + b1.z, a1.w + b1.w};
                half8 h, l;
#pragma unroll
                for (int e = 0; e < 8; ++e) {
                    const _Float16 hv = (_Float16)cs[e];
                    h[e] = hv;
                    l[e] = (_Float16)(cs[e] - (float)hv);
                }
                const int t = b >> 1, nb = (b & 1) * 2 + nbL;
                _Float16* dst =
                    KF + (((size_t)(t * 4 + nb) * 2 + ks) * 2) * 512 + lane * 8;
                *(half8*)dst = h;
                *(half8*)(dst + 512) = l;
            }
            // ---- Q ----
            {
                const int off =
                    2176 + (nbL * 16 + l15) * 68 + ks * 32 + quad * 8;
                const float4 a0 = *(const float4*)(Cb0 + off);
                const float4 a1 = *(const float4*)(Cb0 + off + 4);
                const float4 b0 = *(const float4*)(Cb1 + off);
                const float4 b1 = *(const float4*)(Cb1 + off + 4);
                const float cs[8] = {a0.x + b0.x, a0.y + b0.y, a0.z + b0.z,
                                     a0.w + b0.w, a1.x + b1.x, a1.y + b1.y,
                                     a1.z + b1.z, a1.w + b1.w};
                half8 h, l;
#pragma unroll
                for (int e = 0; e < 8; ++e) {
                    const _Float16 hv = (_Float16)cs[e];
                    h[e] = hv;
                    l[e] = (_Float16)(cs[e] - (float)hv);
                }
                const int rb = b * 2 + nbL;
                _Float16* dst = QF + (((size_t)rb * 2 + ks) * 2) * 512 + lane * 8;
                *(half8*)dst = h;
                *(half8*)(dst + 512) = l;
            }
        }
    }

    // V (mat 2): wave w handles nb in {2w, 2w+1}.
    {
        const int t = b >> 1, ks = b & 1;
#pragma unroll
        for (int nbi = 0; nbi < 2; ++nbi) {
            const int nb = w * 2 + nbi;
            half8 h;
#pragma unroll
            for (int j = 0; j < 8; ++j) {
                const int off = 2 * 2176 + (quad * 8 + j) * 68 + nb * 16 + l15;
                h[j] = (_Float16)(Cb0[off] + Cb1[off]);
            }
            *(half8*)(VF + ((size_t)(t * 4 + nb) * 2 + ks) * 512 + lane * 8) = h;
        }
    }
}

// ---------------------------------------------------------------------------
// Kernel 2: causal flash attention.
// (byte-identical to the round-10 passing version)
// ---------------------------------------------------------------------------
__global__ __launch_bounds__(512, 2) void attn_mfma_kernel(
    const _Float16* __restrict__ QF, const _Float16* __restrict__ KF,
    const _Float16* __restrict__ VF,
    float* __restrict__ pm, float* __restrict__ pl, float* __restrict__ po)
{
    // Ps: [w(8)][mb(2)][16 rows][stride 72 f16] = 36864 B (9216 floats).
    // Merge phase reuses the same region:
    //   mO: [slot(2)][mhalf(2)][32][64] floats  @ 0     (8192 floats)
    //   mM: [slot(2)][mhalf(2)][32]             @ 8192  (128 floats)
    //   mL: [slot(2)][mhalf(2)][32]             @ 8320  (128 floats)
    __shared__ __align__(16) float smemf[9216];
    _Float16* Ps = (_Float16*)smemf;

    const int w = threadIdx.x >> 6, lane = threadIdx.x & 63;
    const int l15 = lane & 15, quad = lane >> 4;
    const int mhalf = w & 1, ss = w >> 1;

    const int b = blockIdx.x;
    const int j = b & 255, hb = b >> 8;
    const int qt = (hb == 0) ? (j >> 1) : (127 - (j >> 1));
    const int sp = (hb << 1) | (j & 1);

    const int qbase = qt * 64;
    const int wrow0 = qbase + mhalf * 32;

    // Q A-frags (hi/lo), loaded once
    half8 qh[2][2], ql[2][2];
#pragma unroll
    for (int mb = 0; mb < 2; ++mb)
#pragma unroll
        for (int ks = 0; ks < 2; ++ks) {
            const int rb = qt * 4 + mhalf * 2 + mb;
            const _Float16* qp = QF + (((size_t)rb * 2 + ks) * 2) * 512 + lane * 8;
            qh[mb][ks] = *(const half8*)qp;
            ql[mb][ks] = *(const half8*)(qp + 512);
        }

    floatx4 O[2][4];
#pragma unroll
    for (int mb = 0; mb < 2; ++mb)
#pragma unroll
        for (int nb = 0; nb < 4; ++nb) O[mb][nb] = 0;
    float mreg[2][4], lreg[2][4];
#pragma unroll
    for (int mb = 0; mb < 2; ++mb)
#pragma unroll
        for (int r = 0; r < 4; ++r) { mreg[mb][r] = -INFINITY; lreg[mb][r] = 0.f; }

    const int t0 = sp + 4 * ss;
    half8 bh[4][2], bl[4][2];
    if (t0 <= qt) {                            // preload first tile's K frags
#pragma unroll
        for (int nb = 0; nb < 4; ++nb)
#pragma unroll
            for (int ks = 0; ks < 2; ++ks) {
                const _Float16* kp =
                    KF + (((size_t)(t0 * 4 + nb) * 2 + ks) * 2) * 512 + lane * 8;
                bh[nb][ks] = *(const half8*)kp;
                bl[nb][ks] = *(const half8*)(kp + 512);
            }
    }

    for (int t = t0; t <= qt; t += 16) {
        const int kb = t * 64;

        // V frags of THIS tile: issued ~600cy before their PV use
        half8 v0r[4], v1r[4];
#pragma unroll
        for (int nb = 0; nb < 4; ++nb) {
            const _Float16* vp = VF + ((size_t)(t * 4 + nb) * 2) * 512 + lane * 8;
            v0r[nb] = *(const half8*)vp;
            v1r[nb] = *(const half8*)(vp + 512);
        }

        // S = Q K^T (hi*hi + hi*lo + lo*hi), scaled into exp2 domain
        float sv[2][4][4];
#pragma unroll
        for (int mb = 0; mb < 2; ++mb)
#pragma unroll
            for (int nb = 0; nb < 4; ++nb) {
                floatx4 s = 0;
#pragma unroll
                for (int ks = 0; ks < 2; ++ks) {
                    s = MFMA16(qh[mb][ks], bh[nb][ks], s);
                    s = MFMA16(qh[mb][ks], bl[nb][ks], s);
                    s = MFMA16(ql[mb][ks], bh[nb][ks], s);
                }
#pragma unroll
                for (int r = 0; r < 4; ++r) sv[mb][nb][r] = s[r] * SCALE_LOG2E;
            }

        // prefetch NEXT tile's K frags (current ones are dead after S)
        if (t + 16 <= qt) {
            const int tn = t + 16;
#pragma unroll
            for (int nb = 0; nb < 4; ++nb)
#pragma unroll
                for (int ks = 0; ks < 2; ++ks) {
                    const _Float16* kp =
                        KF + (((size_t)(tn * 4 + nb) * 2 + ks) * 2) * 512 + lane * 8;
                    bh[nb][ks] = *(const half8*)kp;
                    bl[nb][ks] = *(const half8*)(kp + 512);
                }
        }

        if (kb + 63 > wrow0) {                 // diagonal tile: causal mask
#pragma unroll
            for (int mb = 0; mb < 2; ++mb) {
                const int rowbase = wrow0 + mb * 16 + quad * 4;
#pragma unroll
                for (int nb = 0; nb < 4; ++nb) {
                    const int col = kb + nb * 16 + l15;
#pragma unroll
                    for (int r = 0; r < 4; ++r)
                        if (col > rowbase + r) sv[mb][nb][r] = -INFINITY;
                }
            }
        }

        // online softmax (exp2 domain)
#pragma unroll
        for (int mb = 0; mb < 2; ++mb) {
#pragma unroll
            for (int r = 0; r < 4; ++r) {
                float rm = fmaxf(fmaxf(sv[mb][0][r], sv[mb][1][r]),
                                 fmaxf(sv[mb][2][r], sv[mb][3][r]));
                rm = fmaxf(rm, __shfl_xor(rm, 1));
                rm = fmaxf(rm, __shfl_xor(rm, 2));
                rm = fmaxf(rm, __shfl_xor(rm, 4));
                rm = fmaxf(rm, __shfl_xor(rm, 8));
                const float mnew = fmaxf(mreg[mb][r], rm);
                const float alpha = EXP2F(mreg[mb][r] - mnew);   // -inf -> 0
                float psum = 0.f;
#pragma unroll
                for (int nb = 0; nb < 4; ++nb) {
                    const float p = EXP2F(sv[mb][nb][r] - mnew);  // -inf -> 0
                    psum += p;
                    Ps[(w * 2 + mb) * 1152 + (quad * 4 + r) * 72 + nb * 16 + l15] =
                        (_Float16)p;
                }
                lreg[mb][r] = lreg[mb][r] * alpha + psum;
                mreg[mb][r] = mnew;
#pragma unroll
                for (int nb = 0; nb < 4; ++nb) O[mb][nb][r] *= alpha;
            }
        }

        // P: C-layout -> A-layout via wave-private LDS
        __builtin_amdgcn_wave_barrier();
        WAIT_LGKM0();
        __builtin_amdgcn_wave_barrier();
        half8 pa0[2], pa1[2];
#pragma unroll
        for (int mb = 0; mb < 2; ++mb) {
            const _Float16* pp = Ps + (w * 2 + mb) * 1152 + l15 * 72 + quad * 8;
            pa0[mb] = *(const half8*)pp;
            pa1[mb] = *(const half8*)(pp + 32);
        }

        // PV with the V frags loaded at tile top
#pragma unroll
        for (int nb = 0; nb < 4; ++nb) {
#pragma unroll
            for (int mb = 0; mb < 2; ++mb) {
                O[mb][nb] = MFMA16(pa0[mb], v0r[nb], O[mb][nb]);
                O[mb][nb] = MFMA16(pa1[mb], v1r[nb], O[mb][nb]);
            }
        }
        __builtin_amdgcn_wave_barrier();
    }

    // row-sum l across the 16-lane group (lane-local partials are exact
    // because alpha factors are row-uniform)
#pragma unroll
    for (int mb = 0; mb < 2; ++mb)
#pragma unroll
        for (int r = 0; r < 4; ++r) {
            float s = lreg[mb][r];
            s += __shfl_xor(s, 1);
            s += __shfl_xor(s, 2);
            s += __shfl_xor(s, 4);
            s += __shfl_xor(s, 8);
            lreg[mb][r] = s;
        }

    // ---- 2-round subsplit merge (proven pattern applied twice) ----
    __syncthreads();                           // Ps now dead; reuse as buffers
    // Round A: ss in {2,3} publish to slot ss-2
    if (ss >= 2) {
        const int slot = ss - 2;
#pragma unroll
        for (int mb = 0; mb < 2; ++mb)
#pragma unroll
            for (int r = 0; r < 4; ++r) {
                const int row32 = mb * 16 + quad * 4 + r;
                const int sidx = (slot * 2 + mhalf) * 32 + row32;
#pragma unroll
                for (int nb = 0; nb < 4; ++nb)
                    smemf[sidx * 64 + nb * 16 + l15] = O[mb][nb][r];
                if (l15 == 0) {
                    smemf[8192 + sidx] = mreg[mb][r];
                    smemf[8320 + sidx] = lreg[mb][r];
                }
            }
    }
    __syncthreads();
    if (ss < 2) {                              // ss0 <- slot0(ss2), ss1 <- slot1(ss3)
        const int slot = ss;
#pragma unroll
        for (int mb = 0; mb < 2; ++mb)
#pragma unroll
            for (int r = 0; r < 4; ++r) {
                const int row32 = mb * 16 + quad * 4 + r;
                const int sidx = (slot * 2 + mhalf) * 32 + row32;
                const float m1 = mreg[mb][r], l1 = lreg[mb][r];
                const float m2 = smemf[8192 + sidx];
                const float l2 = smemf[8320 + sidx];
                const float mm = fmaxf(m1, m2);
                const float a1 = (m1 == -INFINITY) ? 0.f : EXP2F(m1 - mm);
                const float a2 = (m2 == -INFINITY) ? 0.f : EXP2F(m2 - mm);
#pragma unroll
                for (int nb = 0; nb < 4; ++nb)
                    O[mb][nb][r] = O[mb][nb][r] * a1 +
                                   smemf[sidx * 64 + nb * 16 + l15] * a2;
                mreg[mb][r] = mm;
                lreg[mb][r] = l1 * a1 + l2 * a2;
            }
    }
    __syncthreads();
    // Round B: ss==1 publish merged state to slot 0
    if (ss == 1) {
#pragma unroll
        for (int mb = 0; mb < 2; ++mb)
#pragma unroll
            for (int r = 0; r < 4; ++r) {
                const int row32 = mb * 16 + quad * 4 + r;
                const int sidx = mhalf * 32 + row32;   // slot 0
#pragma unroll
                for (int nb = 0; nb < 4; ++nb)
                    smemf[sidx * 64 + nb * 16 + l15] = O[mb][nb][r];
                if (l15 == 0) {
                    smemf[8192 + sidx] = mreg[mb][r];
                    smemf[8320 + sidx] = lreg[mb][r];
                }
            }
    }
    __syncthreads();
    if (ss == 0) {                             // final merge + write partials
        const int pidx = qt * NSPLIT + sp;
#pragma unroll
        for (int mb = 0; mb < 2; ++mb)
#pragma unroll
            for (int r = 0; r < 4; ++r) {
                const int row32 = mb * 16 + quad * 4 + r;
                const int sidx = mhalf * 32 + row32;   // slot 0
                const float m1 = mreg[mb][r], l1 = lreg[mb][r];
                const float m2 = smemf[8192 + sidx];
                const float l2 = smemf[8320 + sidx];
                const float mm = fmaxf(m1, m2);
                const float a1 = (m1 == -INFINITY) ? 0.f : EXP2F(m1 - mm);
                const float a2 = (m2 == -INFINITY) ? 0.f : EXP2F(m2 - mm);
                const int row = mhalf * 32 + row32;
                float* dst = po + ((size_t)pidx * 64 + row) * 64;
#pragma unroll
                for (int nb = 0; nb < 4; ++nb)
                    dst[nb * 16 + l15] =
                        O[mb][nb][r] * a1 + smemf[sidx * 64 + nb * 16 + l15] * a2;
                if (l15 == 0) {
                    pm[pidx * 64 + row] = mm;
                    pl[pidx * 64 + row] = l1 * a1 + l2 * a2;
                }
            }
    }
}

// ---------------------------------------------------------------------------
// Kernel 3: merge the NSPLIT split-partials per row (exp2 domain).
// (byte-identical to the round-11 passing float4 version)
// ---------------------------------------------------------------------------
__global__ __launch_bounds__(256) void combine_kernel(
    const float* __restrict__ pm, const float* __restrict__ pl,
    const float* __restrict__ po, float* __restrict__ out)
{
    const int vid = blockIdx.x * 256 + threadIdx.x;    // over T*H/4
    const int row = vid >> 4;                          // 16 float4 per row
    const int d4  = vid & 15;
    const int qt  = row >> 6;
    const int r   = row & 63;

    float mm = -INFINITY;
#pragma unroll
    for (int s = 0; s < NSPLIT; ++s)
        mm = fmaxf(mm, pm[(qt * NSPLIT + s) * 64 + r]);
    float L = 0.f;
    float4 val = make_float4(0.f, 0.f, 0.f, 0.f);
#pragma unroll
    for (int s = 0; s < NSPLIT; ++s) {
        const int p = (qt * NSPLIT + s) * 64 + r;
        const float mp = pm[p];
        const float sc = (mp > -INFINITY) ? EXP2F(mp - mm) : 0.f;
        L += pl[p] * sc;
        const float4 v = *(const float4*)(po + (size_t)p * H_DIM + d4 * 4);
        val.x += v.x * sc; val.y += v.y * sc;
        val.z += v.z * sc; val.w += v.w * sc;
    }
    const float inv = 1.0f / L;
    float4 o; o.x = val.x * inv; o.y = val.y * inv;
    o.z = val.z * inv; o.w = val.w * inv;
    *(float4*)(out + (size_t)row * H_DIM + d4 * 4) = o;
}

// ---------------------------------------------------------------------------
extern "C" void kernel_launch(void* const* d_in, const int* in_sizes, int n_in,
                              void* d_out, int out_size, void* d_ws, size_t ws_size,
                              hipStream_t stream)
{
    const float* tokens = (const float*)d_in[0];
    const float* Wk = (const float*)d_in[1];
    const float* Wq = (const float*)d_in[2];
    const float* Wv = (const float*)d_in[3];
    float* out = (float*)d_out;

    // ws layout (bytes), total 14.25 MB:
    //   WF @0 (576KB) | KF @1MB (2MB) | QF @3MB (2MB) | VF @5MB (1MB)
    //   pm @6MB (128KB) | pl @6.125MB (128KB) | po @6.25MB (8MB)
    char* ws = (char*)d_ws;
    const size_t MB = 1024 * 1024;
    _Float16* WF = (_Float16*)(ws + 0 * MB);
    _Float16* KF = (_Float16*)(ws + 1 * MB);
    _Float16* QF = (_Float16*)(ws + 3 * MB);
    _Float16* VF = (_Float16*)(ws + 5 * MB);
    float* pm = (float*)(ws + 6 * MB);
    float* pl = (float*)(ws + 6 * MB + 128 * 1024);
    float* po = (float*)(ws + 6 * MB + 256 * 1024);

    wconvert_kernel<<<288, 64, 0, stream>>>(Wk, Wq, Wv, WF);

    proj_kernel<<<256, 128, 0, stream>>>(tokens, WF, KF, QF, VF);

    attn_mfma_kernel<<<128 * NSPLIT, 512, 0, stream>>>(QF, KF, VF, pm, pl, po);

    combine_kernel<<<T_TOK * H_DIM / 4 / 256, 256, 0, stream>>>(pm, pl, po, out);
}

// Round 6
// 116.977 us; speedup vs baseline: 1.2885x; 1.0758x over previous
//
#include <hip/hip_runtime.h>
#include <math.h>

#define T_TOK 8192
#define C_DIM 768
#define H_DIM 64
// reference MULTIPLIES by c**0.5; we work in exp2 domain: scale * log2(e)
#define SCALE_LOG2E (27.712812921102035f * 1.4426950408889634f)
#define NSPLIT 4

typedef _Float16 half8 __attribute__((ext_vector_type(8)));
typedef _Float16 half2t __attribute__((ext_vector_type(2)));
typedef float floatx4 __attribute__((ext_vector_type(4)));

#define MFMA16(a, b, c) __builtin_amdgcn_mfma_f32_16x16x32_f16(a, b, c, 0, 0, 0)
// wait lgkmcnt(0) only: vmcnt=0x3F, expcnt=7, lgkm=0
#define WAIT_LGKM0() __builtin_amdgcn_s_waitcnt(0xC07F)
#define EXP2F(x) __builtin_amdgcn_exp2f(x)

// global_load_lds: width 16B/lane; LDS dest = wave-uniform base + lane*16 (HW),
// global src = per-lane address (we pass base + lane*8 f16 = lane*16 B).
typedef __attribute__((address_space(3))) void lds_void;
typedef const __attribute__((address_space(1))) void gbl_void;
#define GLOAD16(gp, lp) \
    __builtin_amdgcn_global_load_lds((gbl_void*)(gp), (lds_void*)(lp), 16, 0, 0)

template <int K> struct IC { static constexpr int v = K; };

// Fragment layouts in workspace (all 1KB frags, perfectly coalesced b128/lane):
//   WF[mat][kt(24)][nb(4)][hl(2)][512 f16]   = W[kt*32+quad*8+j][nb*16+l15]
//   KF[t(128)][nb(4)][ks(2)][hl(2)][512 f16] = K[t*64+nb*16+l15][ks*32+quad*8+j]
//   QF[rb(512)][ks(2)][hl(2)][512 f16]       = Q[rb*16+l15][ks*32+quad*8+j]
//   VF[t(128)][nb(4)][ks(2)][512 f16]        = V[t*64+ks*32+quad*8+j][nb*16+l15]

// ---------------------------------------------------------------------------
// Kernel 0: W fp32 -> hi/lo f16 B-frags.  288 blocks x 64 threads.
// (byte-identical to the round-10 passing version)
// ---------------------------------------------------------------------------
__global__ __launch_bounds__(64) void wconvert_kernel(
    const float* __restrict__ Wk, const float* __restrict__ Wq,
    const float* __restrict__ Wv, _Float16* __restrict__ WF)
{
    const int b = blockIdx.x;                  // 3*24*4
    const int mat = b / 96, rem = b % 96, kt = rem >> 2, nb = rem & 3;
    const int lane = threadIdx.x & 63, l15 = lane & 15, quad = lane >> 4;
    const float* __restrict__ W = (mat == 0) ? Wk : (mat == 1) ? Wq : Wv;

    half8 h, l;
#pragma unroll
    for (int j = 0; j < 8; ++j) {
        const float v = W[(kt * 32 + quad * 8 + j) * H_DIM + nb * 16 + l15];
        const _Float16 hv = (_Float16)v;
        h[j] = hv;
        l[j] = (_Float16)(v - (float)hv);
    }
    _Float16* dst = WF + ((((size_t)mat * 24 + kt) * 4 + nb) * 2) * 512 + lane * 8;
    *(half8*)dst = h;
    *(half8*)(dst + 512) = l;
}

// ---------------------------------------------------------------------------
// Kernel 1: FUSED MFMA projection, W staged through LDS, SPLIT-K x2.
// (byte-identical to the round-5 passing version)
// ---------------------------------------------------------------------------
__global__ __launch_bounds__(128, 1) void proj_kernel(
    const float* __restrict__ tokens, const _Float16* __restrict__ WF,
    _Float16* __restrict__ KF, _Float16* __restrict__ QF,
    _Float16* __restrict__ VF)
{
    // W dbufs: wave0 [0,40960), wave1 [40960,81920).
    // Epilogue reuse: Cb0 @0 (26112 B), Cb1 @26112 (26112 B).
    __shared__ __align__(16) char smemraw[81920];
    const int b = blockIdx.x;                  // 256 blocks, 32 rows each
    const int tid = threadIdx.x;
    const int w = tid >> 6;                    // wave id 0/1 (kt-split)
    const int lane = tid & 63, l15 = lane & 15, quad = lane >> 4;
    const int row0 = b * 32;
    const int kt0 = w * 12;                    // this wave's first kt

    floatx4 acc[3][2][4];
#pragma unroll
    for (int mat = 0; mat < 3; ++mat)
#pragma unroll
        for (int mb = 0; mb < 2; ++mb)
#pragma unroll
            for (int nb = 0; nb < 4; ++nb) acc[mat][mb][nb] = 0;

    // this wave's token columns: [kt0*32, kt0*32 + 384)
    const float* __restrict__ xb0 =
        tokens + (size_t)(row0 + l15) * C_DIM + kt0 * 32 + quad * 8;
    const float* __restrict__ xb1 =
        tokens + (size_t)(row0 + 16 + l15) * C_DIM + kt0 * 32 + quad * 8;

    _Float16* const wavebuf = (_Float16*)(smemraw + w * 40960);

    // LDS slot map within one 20KB buffer (f16 elem offsets, 512 per frag):
    //   K  hi/lo: (nb*2+hl)*512      (slots 0..7)
    //   Q  hi/lo: (8+nb*2+hl)*512    (slots 8..15)
    //   V  hi   : (16+nb)*512        (slots 16..19)
    // Global frag base (f16 elems): (((mat*24+kt)*4+nb)*2 + hl)*512 + lane*8.

    // ---- prologue: DMA W(kt0) into slot 0, then fill 4-deep token FIFO ----
    {
#pragma unroll
        for (int nb = 0; nb < 4; ++nb) {
            const _Float16* gK =
                WF + (size_t)((kt0 * 4 + nb) * 2) * 512 + lane * 8;
            const _Float16* gQ =
                WF + (size_t)(((24 + kt0) * 4 + nb) * 2) * 512 + lane * 8;
            const _Float16* gV =
                WF + (size_t)(((48 + kt0) * 4 + nb) * 2) * 512 + lane * 8;
            GLOAD16(gK,       wavebuf + (nb * 2 + 0) * 512);
            GLOAD16(gK + 512, wavebuf + (nb * 2 + 1) * 512);
            GLOAD16(gQ,       wavebuf + (8 + nb * 2 + 0) * 512);
            GLOAD16(gQ + 512, wavebuf + (8 + nb * 2 + 1) * 512);
            GLOAD16(gV,       wavebuf + (16 + nb) * 512);
        }
    }
    __builtin_amdgcn_sched_barrier(0);
    float4 tf[4][4];
#pragma unroll
    for (int d = 0; d < 4; ++d) {
        tf[d][0] = *(const float4*)(xb0 + d * 32);
        tf[d][1] = *(const float4*)(xb0 + d * 32 + 4);
        tf[d][2] = *(const float4*)(xb1 + d * 32);
        tf[d][3] = *(const float4*)(xb1 + d * 32 + 4);
    }
    __builtin_amdgcn_sched_barrier(0);

    auto iter = [&](auto kc) {
        constexpr int ktl = decltype(kc)::v;   // local kt 0..11
        constexpr int slot = ktl & 3;
        constexpr int curb = ktl & 1;
        _Float16* wb  = wavebuf + curb * 10240;        // 20480 B = 10240 f16
        _Float16* wbn = wavebuf + (curb ^ 1) * 10240;

        // ---- region A0: snapshot CURRENT tokens before any refill ----
        __builtin_amdgcn_sched_barrier(0);
        const float4 x0 = tf[slot][0], x1 = tf[slot][1];
        const float4 x2 = tf[slot][2], x3 = tf[slot][3];
        __builtin_amdgcn_sched_barrier(0);

        // ---- region A1: DMA W(kt0+ktl+1) into the other buffer ----
        if constexpr (ktl < 11) {
            const int ktn = kt0 + ktl + 1;
#pragma unroll
            for (int nb = 0; nb < 4; ++nb) {
                const _Float16* gK =
                    WF + (size_t)((ktn * 4 + nb) * 2) * 512 + lane * 8;
                const _Float16* gQ =
                    WF + (size_t)(((24 + ktn) * 4 + nb) * 2) * 512 + lane * 8;
                const _Float16* gV =
                    WF + (size_t)(((48 + ktn) * 4 + nb) * 2) * 512 + lane * 8;
                GLOAD16(gK,       wbn + (nb * 2 + 0) * 512);
                GLOAD16(gK + 512, wbn + (nb * 2 + 1) * 512);
                GLOAD16(gQ,       wbn + (8 + nb * 2 + 0) * 512);
                GLOAD16(gQ + 512, wbn + (8 + nb * 2 + 1) * 512);
                GLOAD16(gV,       wbn + (16 + nb) * 512);
            }
        }
        __builtin_amdgcn_sched_barrier(0);
        // ---- region A2: refill token FIFO slot with ktl+4 ----
        if constexpr (ktl + 4 < 12) {
            constexpr int ktf = ktl + 4;
            tf[slot][0] = *(const float4*)(xb0 + ktf * 32);
            tf[slot][1] = *(const float4*)(xb0 + ktf * 32 + 4);
            tf[slot][2] = *(const float4*)(xb1 + ktf * 32);
            tf[slot][3] = *(const float4*)(xb1 + ktf * 32 + 4);
        }
        __builtin_amdgcn_sched_barrier(0);
        // ---- counted wait: W(kt0+ktl) complete, token FIFO in flight ----
        constexpr int VMN = (ktl == 0)
            ? 40
            : ((ktl <= 8 ? 4 : 0) + (ktl <= 10 ? 20 : 0) + (ktl <= 7 ? 4 : 0));
        asm volatile("s_waitcnt vmcnt(%0)" ::"n"(VMN));
        __builtin_amdgcn_sched_barrier(0);

        // ---- region B: convert A-tiles, ds_read W frags, 56 MFMA ----
        half8 ah[2], al[2];
        {
            const float xs0[8] = {x0.x, x0.y, x0.z, x0.w, x1.x, x1.y, x1.z, x1.w};
            const float xs1[8] = {x2.x, x2.y, x2.z, x2.w, x3.x, x3.y, x3.z, x3.w};
#pragma unroll
            for (int e = 0; e < 8; ++e) {
                _Float16 hv = (_Float16)xs0[e];
                ah[0][e] = hv;
                al[0][e] = (_Float16)(xs0[e] - (float)hv);
                hv = (_Float16)xs1[e];
                ah[1][e] = hv;
                al[1][e] = (_Float16)(xs1[e] - (float)hv);
            }
        }
        const _Float16* wp = wb + lane * 8;
#pragma unroll
        for (int nb = 0; nb < 4; ++nb) {
            const half8 kh = *(const half8*)(wp + (nb * 2 + 0) * 512);
            const half8 kl = *(const half8*)(wp + (nb * 2 + 1) * 512);
            const half8 qh = *(const half8*)(wp + (8 + nb * 2 + 0) * 512);
            const half8 ql = *(const half8*)(wp + (8 + nb * 2 + 1) * 512);
            const half8 vh = *(const half8*)(wp + (16 + nb) * 512);
#pragma unroll
            for (int mb = 0; mb < 2; ++mb) {
                acc[0][mb][nb] = MFMA16(ah[mb], kh, acc[0][mb][nb]);
                acc[0][mb][nb] = MFMA16(ah[mb], kl, acc[0][mb][nb]);
                acc[0][mb][nb] = MFMA16(al[mb], kh, acc[0][mb][nb]);
                acc[1][mb][nb] = MFMA16(ah[mb], qh, acc[1][mb][nb]);
                acc[1][mb][nb] = MFMA16(ah[mb], ql, acc[1][mb][nb]);
                acc[1][mb][nb] = MFMA16(al[mb], qh, acc[1][mb][nb]);
                acc[2][mb][nb] = MFMA16(ah[mb], vh, acc[2][mb][nb]);
            }
        }
    };
#define PITER(k) iter(IC<k>{});
    PITER(0)  PITER(1)  PITER(2)  PITER(3)  PITER(4)  PITER(5)
    PITER(6)  PITER(7)  PITER(8)  PITER(9)  PITER(10) PITER(11)
#undef PITER

    // Both waves done (drains all vm/lgkm) before Cb regions (which alias
    // the other wave's W dbuf space) are written.
    __syncthreads();

    // ---- wave-private fp32 partials into disjoint Cb regions ----
    float* Cb0 = (float*)smemraw;              // wave0 partial
    float* Cb1 = (float*)(smemraw + 26112);    // wave1 partial
    float* Cbw = w ? Cb1 : Cb0;
#pragma unroll
    for (int mat = 0; mat < 3; ++mat)
#pragma unroll
        for (int mb = 0; mb < 2; ++mb)
#pragma unroll
            for (int nb = 0; nb < 4; ++nb)
#pragma unroll
                for (int r = 0; r < 4; ++r)
                    Cbw[mat * 2176 + (mb * 16 + quad * 4 + r) * 68 + nb * 16 + l15] =
                        acc[mat][mb][nb][r];
    __syncthreads();

    // ---- merged epilogue (element = Cb0 + Cb1), work split by wave ----
    // K (mat 0) and Q (mat 1): wave w handles nbL = w.
    {
        const int nbL = w;
#pragma unroll
        for (int ks = 0; ks < 2; ++ks) {
            // ---- K ----
            {
                const int off = (nbL * 16 + l15) * 68 + ks * 32 + quad * 8;
                const float4 a0 = *(const float4*)(Cb0 + off);
                const float4 a1 = *(const float4*)(Cb0 + off + 4);
                const float4 b0 = *(const float4*)(Cb1 + off);
                const float4 b1 = *(const float4*)(Cb1 + off + 4);
                const float cs[8] = {a0.x + b0.x, a0.y + b0.y, a0.z + b0.z,
                                     a0.w + b0.w, a1.x + b1.x, a1.y + b1.y,
                                     a1.z + b1.z, a1.w + b1.w};
                half8 h, l;
#pragma unroll
                for (int e = 0; e < 8; ++e) {
                    const _Float16 hv = (_Float16)cs[e];
                    h[e] = hv;
                    l[e] = (_Float16)(cs[e] - (float)hv);
                }
                const int t = b >> 1, nb = (b & 1) * 2 + nbL;
                _Float16* dst =
                    KF + (((size_t)(t * 4 + nb) * 2 + ks) * 2) * 512 + lane * 8;
                *(half8*)dst = h;
                *(half8*)(dst + 512) = l;
            }
            // ---- Q ----
            {
                const int off =
                    2176 + (nbL * 16 + l15) * 68 + ks * 32 + quad * 8;
                const float4 a0 = *(const float4*)(Cb0 + off);
                const float4 a1 = *(const float4*)(Cb0 + off + 4);
                const float4 b0 = *(const float4*)(Cb1 + off);
                const float4 b1 = *(const float4*)(Cb1 + off + 4);
                const float cs[8] = {a0.x + b0.x, a0.y + b0.y, a0.z + b0.z,
                                     a0.w + b0.w, a1.x + b1.x, a1.y + b1.y,
                                     a1.z + b1.z, a1.w + b1.w};
                half8 h, l;
#pragma unroll
                for (int e = 0; e < 8; ++e) {
                    const _Float16 hv = (_Float16)cs[e];
                    h[e] = hv;
                    l[e] = (_Float16)(cs[e] - (float)hv);
                }
                const int rb = b * 2 + nbL;
                _Float16* dst = QF + (((size_t)rb * 2 + ks) * 2) * 512 + lane * 8;
                *(half8*)dst = h;
                *(half8*)(dst + 512) = l;
            }
        }
    }

    // V (mat 2): wave w handles nb in {2w, 2w+1}.
    {
        const int t = b >> 1, ks = b & 1;
#pragma unroll
        for (int nbi = 0; nbi < 2; ++nbi) {
            const int nb = w * 2 + nbi;
            half8 h;
#pragma unroll
            for (int j = 0; j < 8; ++j) {
                const int off = 2 * 2176 + (quad * 8 + j) * 68 + nb * 16 + l15;
                h[j] = (_Float16)(Cb0[off] + Cb1[off]);
            }
            *(half8*)(VF + ((size_t)(t * 4 + nb) * 2 + ks) * 512 + lane * 8) = h;
        }
    }
}

// ---------------------------------------------------------------------------
// Kernel 2: causal flash attention, SWAPPED QK^T (S^T = K·Q^T).
// Round-5 analysis: softmax was issue-bound (~230 VALU + 64 DS ops/tile vs
// ~310cy MFMA): per-(row,r) shfl reduces (32 shfl/tile), 8 alphas, and 32
// scalar 2B Ps stores.  Computing S^T instead (A=K frag, B=Q frag — SAME
// workspace frags, A/B layouts identical) makes each lane own 16 keys of ONE
// q-row (q=l15): row-max = 15 in-reg fmax + 2 shfl; 2 alphas/tile; P-store
// becomes 4 contiguous f16 per (qb,kb2) -> cvt_pkrtz x2 + one b64 write (8
// vs 32 stores).  alpha redistributed to O's C-layout rows via tiny LDS
// bounce (broadcast reads); m/l redistributed once at loop exit.  P-read,
// PV, V frags, merge phase unchanged.  S/m/alpha bit-identical (positional
// HW dot order); P packed RTZ (<=2^-11 rel on p in [0,1]).
// ---------------------------------------------------------------------------
__global__ __launch_bounds__(512, 2) void attn_mfma_kernel(
    const _Float16* __restrict__ QF, const _Float16* __restrict__ KF,
    const _Float16* __restrict__ VF,
    float* __restrict__ pm, float* __restrict__ pl, float* __restrict__ po)
{
    // smemf: Ps [0,9216) | aL [9216,9472) | mP [9472,9728) | lP [9728,9984)
    // Ps: [w(8)][qb(2)][16 rows][stride 72 f16] = 36864 B.
    // Merge phase reuses [0,8448) as mO/mM/mL exactly as before.
    __shared__ __align__(16) float smemf[9984];
    _Float16* Ps = (_Float16*)smemf;
    float* aL = smemf + 9216;                  // [w][32] alpha (C-row bounce)
    float* mP = smemf + 9472;                  // [w][32] m publish
    float* lP = smemf + 9728;                  // [w][32] l publish

    const int w = threadIdx.x >> 6, lane = threadIdx.x & 63;
    const int l15 = lane & 15, quad = lane >> 4;
    const int mhalf = w & 1, ss = w >> 1;

    const int b = blockIdx.x;
    const int j = b & 255, hb = b >> 8;
    const int qt = (hb == 0) ? (j >> 1) : (127 - (j >> 1));
    const int sp = (hb << 1) | (j & 1);

    const int qbase = qt * 64;
    const int wrow0 = qbase + mhalf * 32;

    // Q frags (hi/lo), loaded once — now used as the B-operand of S^T.
    half8 qh[2][2], ql[2][2];
#pragma unroll
    for (int mb = 0; mb < 2; ++mb)
#pragma unroll
        for (int ks = 0; ks < 2; ++ks) {
            const int rb = qt * 4 + mhalf * 2 + mb;
            const _Float16* qp = QF + (((size_t)rb * 2 + ks) * 2) * 512 + lane * 8;
            qh[mb][ks] = *(const half8*)qp;
            ql[mb][ks] = *(const half8*)(qp + 512);
        }

    floatx4 O[2][4];
#pragma unroll
    for (int mb = 0; mb < 2; ++mb)
#pragma unroll
        for (int nb = 0; nb < 4; ++nb) O[mb][nb] = 0;
    // per-lane online-softmax state for q = qb*16 + l15 (2 q-blocks)
    float mq[2] = {-INFINITY, -INFINITY};
    float lq[2] = {0.f, 0.f};

    const int t0 = sp + 4 * ss;
    half8 kh[4][2], kl[4][2];                  // K frags, A-operand of S^T
    if (t0 <= qt) {                            // preload first tile's K frags
#pragma unroll
        for (int kb2 = 0; kb2 < 4; ++kb2)
#pragma unroll
            for (int ks = 0; ks < 2; ++ks) {
                const _Float16* kp =
                    KF + (((size_t)(t0 * 4 + kb2) * 2 + ks) * 2) * 512 + lane * 8;
                kh[kb2][ks] = *(const half8*)kp;
                kl[kb2][ks] = *(const half8*)(kp + 512);
            }
    }

    for (int t = t0; t <= qt; t += 16) {
        const int kb = t * 64;

        // V frags of THIS tile: issued ~600cy before their PV use
        half8 v0r[4], v1r[4];
#pragma unroll
        for (int nb = 0; nb < 4; ++nb) {
            const _Float16* vp = VF + ((size_t)(t * 4 + nb) * 2) * 512 + lane * 8;
            v0r[nb] = *(const half8*)vp;
            v1r[nb] = *(const half8*)(vp + 512);
        }

        // S^T = K·Q^T (same three terms as before: QhKh + QhKl + QlKh),
        // scaled into exp2 domain.  Lane holds S^T[key=kb2*16+quad*4+r][q=l15].
        float sv[4][2][4];
#pragma unroll
        for (int kb2 = 0; kb2 < 4; ++kb2)
#pragma unroll
            for (int qb = 0; qb < 2; ++qb) {
                floatx4 s = 0;
#pragma unroll
                for (int ks = 0; ks < 2; ++ks) {
                    s = MFMA16(kh[kb2][ks], qh[qb][ks], s);
                    s = MFMA16(kl[kb2][ks], qh[qb][ks], s);
                    s = MFMA16(kh[kb2][ks], ql[qb][ks], s);
                }
#pragma unroll
                for (int r = 0; r < 4; ++r) sv[kb2][qb][r] = s[r] * SCALE_LOG2E;
            }

        // prefetch NEXT tile's K frags (current ones are dead after S^T)
        if (t + 16 <= qt) {
            const int tn = t + 16;
#pragma unroll
            for (int kb2 = 0; kb2 < 4; ++kb2)
#pragma unroll
                for (int ks = 0; ks < 2; ++ks) {
                    const _Float16* kp =
                        KF + (((size_t)(tn * 4 + kb2) * 2 + ks) * 2) * 512 + lane * 8;
                    kh[kb2][ks] = *(const half8*)kp;
                    kl[kb2][ks] = *(const half8*)(kp + 512);
                }
        }

        if (kb + 63 > wrow0) {                 // diagonal tile: causal mask
#pragma unroll
            for (int qb = 0; qb < 2; ++qb) {
                const int q = wrow0 + qb * 16 + l15;
#pragma unroll
                for (int kb2 = 0; kb2 < 4; ++kb2) {
                    const int keyb = kb + kb2 * 16 + quad * 4;
#pragma unroll
                    for (int r = 0; r < 4; ++r)
                        if (keyb + r > q) sv[kb2][qb][r] = -INFINITY;
                }
            }
        }

        // online softmax — reduction axis (keys) is lane-local
#pragma unroll
        for (int qb = 0; qb < 2; ++qb) {
            float rm = sv[0][qb][0];
#pragma unroll
            for (int kb2 = 0; kb2 < 4; ++kb2)
#pragma unroll
                for (int r = 0; r < 4; ++r) rm = fmaxf(rm, sv[kb2][qb][r]);
            rm = fmaxf(rm, __shfl_xor(rm, 16));
            rm = fmaxf(rm, __shfl_xor(rm, 32));
            const float mnew = fmaxf(mq[qb], rm);      // rm finite always
            const float alpha = EXP2F(mq[qb] - mnew);  // -inf -> 0
            if (quad == 0) aL[w * 32 + qb * 16 + l15] = alpha;
            float psum = 0.f;
#pragma unroll
            for (int kb2 = 0; kb2 < 4; ++kb2) {
                const float p0 = EXP2F(sv[kb2][qb][0] - mnew);
                const float p1 = EXP2F(sv[kb2][qb][1] - mnew);
                const float p2 = EXP2F(sv[kb2][qb][2] - mnew);
                const float p3 = EXP2F(sv[kb2][qb][3] - mnew);
                psum += (p0 + p1) + (p2 + p3);
                const unsigned u0 =
                    __builtin_bit_cast(unsigned, __builtin_amdgcn_cvt_pkrtz(p0, p1));
                const unsigned u1 =
                    __builtin_bit_cast(unsigned, __builtin_amdgcn_cvt_pkrtz(p2, p3));
                uint2* dst = (uint2*)(Ps + (w * 2 + qb) * 1152 + l15 * 72 +
                                      kb2 * 16 + quad * 4);
                *dst = make_uint2(u0, u1);
            }
            lq[qb] = lq[qb] * alpha + psum;    // alpha quad-uniform -> exact
            mq[qb] = mnew;
        }

        // fence: Ps + aL writes visible to this wave's reads
        __builtin_amdgcn_wave_barrier();
        WAIT_LGKM0();
        __builtin_amdgcn_wave_barrier();

        // O rescale with alpha redistributed to C-layout rows (broadcast read)
        floatx4 aO[2];
#pragma unroll
        for (int mb = 0; mb < 2; ++mb)
            aO[mb] = *(const floatx4*)(aL + w * 32 + mb * 16 + quad * 4);
#pragma unroll
        for (int mb = 0; mb < 2; ++mb)
#pragma unroll
            for (int nb = 0; nb < 4; ++nb)
#pragma unroll
                for (int r = 0; r < 4; ++r) O[mb][nb][r] *= aO[mb][r];

        // P A-frags (read side unchanged)
        half8 pa0[2], pa1[2];
#pragma unroll
        for (int mb = 0; mb < 2; ++mb) {
            const _Float16* pp = Ps + (w * 2 + mb) * 1152 + l15 * 72 + quad * 8;
            pa0[mb] = *(const half8*)pp;
            pa1[mb] = *(const half8*)(pp + 32);
        }

        // PV with the V frags loaded at tile top (unchanged)
#pragma unroll
        for (int nb = 0; nb < 4; ++nb) {
#pragma unroll
            for (int mb = 0; mb < 2; ++mb) {
                O[mb][nb] = MFMA16(pa0[mb], v0r[nb], O[mb][nb]);
                O[mb][nb] = MFMA16(pa1[mb], v1r[nb], O[mb][nb]);
            }
        }
        __builtin_amdgcn_wave_barrier();
    }

    // cross-quad l reduce (alpha factors row-uniform -> partials exact),
    // then publish m,l and reload in C-layout for the merge phase.
#pragma unroll
    for (int qb = 0; qb < 2; ++qb) {
        lq[qb] += __shfl_xor(lq[qb], 16);
        lq[qb] += __shfl_xor(lq[qb], 32);
    }
    if (quad == 0) {
#pragma unroll
        for (int qb = 0; qb < 2; ++qb) {
            mP[w * 32 + qb * 16 + l15] = mq[qb];
            lP[w * 32 + qb * 16 + l15] = lq[qb];
        }
    }
    __builtin_amdgcn_wave_barrier();
    WAIT_LGKM0();
    __builtin_amdgcn_wave_barrier();
    float mreg[2][4], lreg[2][4];
#pragma unroll
    for (int mb = 0; mb < 2; ++mb) {
        const floatx4 mv = *(const floatx4*)(mP + w * 32 + mb * 16 + quad * 4);
        const floatx4 lv = *(const floatx4*)(lP + w * 32 + mb * 16 + quad * 4);
#pragma unroll
        for (int r = 0; r < 4; ++r) { mreg[mb][r] = mv[r]; lreg[mb][r] = lv[r]; }
    }

    // ---- 2-round subsplit merge (unchanged) ----
    __syncthreads();                           // Ps now dead; reuse as buffers
    // Round A: ss in {2,3} publish to slot ss-2
    if (ss >= 2) {
        const int slot = ss - 2;
#pragma unroll
        for (int mb = 0; mb < 2; ++mb)
#pragma unroll
            for (int r = 0; r < 4; ++r) {
                const int row32 = mb * 16 + quad * 4 + r;
                const int sidx = (slot * 2 + mhalf) * 32 + row32;
#pragma unroll
                for (int nb = 0; nb < 4; ++nb)
                    smemf[sidx * 64 + nb * 16 + l15] = O[mb][nb][r];
                if (l15 == 0) {
                    smemf[8192 + sidx] = mreg[mb][r];
                    smemf[8320 + sidx] = lreg[mb][r];
                }
            }
    }
    __syncthreads();
    if (ss < 2) {                              // ss0 <- slot0(ss2), ss1 <- slot1(ss3)
        const int slot = ss;
#pragma unroll
        for (int mb = 0; mb < 2; ++mb)
#pragma unroll
            for (int r = 0; r < 4; ++r) {
                const int row32 = mb * 16 + quad * 4 + r;
                const int sidx = (slot * 2 + mhalf) * 32 + row32;
                const float m1 = mreg[mb][r], l1 = lreg[mb][r];
                const float m2 = smemf[8192 + sidx];
                const float l2 = smemf[8320 + sidx];
                const float mm = fmaxf(m1, m2);
                const float a1 = (m1 == -INFINITY) ? 0.f : EXP2F(m1 - mm);
                const float a2 = (m2 == -INFINITY) ? 0.f : EXP2F(m2 - mm);
#pragma unroll
                for (int nb = 0; nb < 4; ++nb)
                    O[mb][nb][r] = O[mb][nb][r] * a1 +
                                   smemf[sidx * 64 + nb * 16 + l15] * a2;
                mreg[mb][r] = mm;
                lreg[mb][r] = l1 * a1 + l2 * a2;
            }
    }
    __syncthreads();
    // Round B: ss==1 publish merged state to slot 0
    if (ss == 1) {
#pragma unroll
        for (int mb = 0; mb < 2; ++mb)
#pragma unroll
            for (int r = 0; r < 4; ++r) {
                const int row32 = mb * 16 + quad * 4 + r;
                const int sidx = mhalf * 32 + row32;   // slot 0
#pragma unroll
                for (int nb = 0; nb < 4; ++nb)
                    smemf[sidx * 64 + nb * 16 + l15] = O[mb][nb][r];
                if (l15 == 0) {
                    smemf[8192 + sidx] = mreg[mb][r];
                    smemf[8320 + sidx] = lreg[mb][r];
                }
            }
    }
    __syncthreads();
    if (ss == 0) {                             // final merge + write partials
        const int pidx = qt * NSPLIT + sp;
#pragma unroll
        for (int mb = 0; mb < 2; ++mb)
#pragma unroll
            for (int r = 0; r < 4; ++r) {
                const int row32 = mb * 16 + quad * 4 + r;
                const int sidx = mhalf * 32 + row32;   // slot 0
                const float m1 = mreg[mb][r], l1 = lreg[mb][r];
                const float m2 = smemf[8192 + sidx];
                const float l2 = smemf[8320 + sidx];
                const float mm = fmaxf(m1, m2);
                const float a1 = (m1 == -INFINITY) ? 0.f : EXP2F(m1 - mm);
                const float a2 = (m2 == -INFINITY) ? 0.f : EXP2F(m2 - mm);
                const int row = mhalf * 32 + row32;
                float* dst = po + ((size_t)pidx * 64 + row) * 64;
#pragma unroll
                for (int nb = 0; nb < 4; ++nb)
                    dst[nb * 16 + l15] =
                        O[mb][nb][r] * a1 + smemf[sidx * 64 + nb * 16 + l15] * a2;
                if (l15 == 0) {
                    pm[pidx * 64 + row] = mm;
                    pl[pidx * 64 + row] = l1 * a1 + l2 * a2;
                }
            }
    }
}

// ---------------------------------------------------------------------------
// Kernel 3: merge the NSPLIT split-partials per row (exp2 domain).
// (byte-identical to the round-11 passing float4 version)
// ---------------------------------------------------------------------------
__global__ __launch_bounds__(256) void combine_kernel(
    const float* __restrict__ pm, const float* __restrict__ pl,
    const float* __restrict__ po, float* __restrict__ out)
{
    const int vid = blockIdx.x * 256 + threadIdx.x;    // over T*H/4
    const int row = vid >> 4;                          // 16 float4 per row
    const int d4  = vid & 15;
    const int qt  = row >> 6;
    const int r   = row & 63;

    float mm = -INFINITY;
#pragma unroll
    for (int s = 0; s < NSPLIT; ++s)
        mm = fmaxf(mm, pm[(qt * NSPLIT + s) * 64 + r]);
    float L = 0.f;
    float4 val = make_float4(0.f, 0.f, 0.f, 0.f);
#pragma unroll
    for (int s = 0; s < NSPLIT; ++s) {
        const int p = (qt * NSPLIT + s) * 64 + r;
        const float mp = pm[p];
        const float sc = (mp > -INFINITY) ? EXP2F(mp - mm) : 0.f;
        L += pl[p] * sc;
        const float4 v = *(const float4*)(po + (size_t)p * H_DIM + d4 * 4);
        val.x += v.x * sc; val.y += v.y * sc;
        val.z += v.z * sc; val.w += v.w * sc;
    }
    const float inv = 1.0f / L;
    float4 o; o.x = val.x * inv; o.y = val.y * inv;
    o.z = val.z * inv; o.w = val.w * inv;
    *(float4*)(out + (size_t)row * H_DIM + d4 * 4) = o;
}

// ---------------------------------------------------------------------------
extern "C" void kernel_launch(void* const* d_in, const int* in_sizes, int n_in,
                              void* d_out, int out_size, void* d_ws, size_t ws_size,
                              hipStream_t stream)
{
    const float* tokens = (const float*)d_in[0];
    const float* Wk = (const float*)d_in[1];
    const float* Wq = (const float*)d_in[2];
    const float* Wv = (const float*)d_in[3];
    float* out = (float*)d_out;

    // ws layout (bytes), total 14.25 MB:
    //   WF @0 (576KB) | KF @1MB (2MB) | QF @3MB (2MB) | VF @5MB (1MB)
    //   pm @6MB (128KB) | pl @6.125MB (128KB) | po @6.25MB (8MB)
    char* ws = (char*)d_ws;
    const size_t MB = 1024 * 1024;
    _Float16* WF = (_Float16*)(ws + 0 * MB);
    _Float16* KF = (_Float16*)(ws + 1 * MB);
    _Float16* QF = (_Float16*)(ws + 3 * MB);
    _Float16* VF = (_Float16*)(ws + 5 * MB);
    float* pm = (float*)(ws + 6 * MB);
    float* pl = (float*)(ws + 6 * MB + 128 * 1024);
    float* po = (float*)(ws + 6 * MB + 256 * 1024);

    wconvert_kernel<<<288, 64, 0, stream>>>(Wk, Wq, Wv, WF);

    proj_kernel<<<256, 128, 0, stream>>>(tokens, WF, KF, QF, VF);

    attn_mfma_kernel<<<128 * NSPLIT, 512, 0, stream>>>(QF, KF, VF, pm, pl, po);

    combine_kernel<<<T_TOK * H_DIM / 4 / 256, 256, 0, stream>>>(pm, pl, po, out);
}